// Round 8
// baseline (216.742 us; speedup 1.0000x reference)
//
#include <hip/hip_runtime.h>
#include <hip/hip_bf16.h>
#include <math.h>

#define NB 8
#define NN 4096
#define KK 16
#define MM (NB*NN)
#define CH 32
#define SLOTS 17
#define NCLS 40
#define BIG 3.0e38f
#define CAP 96         // survivors ~40 incl. self w/ half-sample T; ballot-push drops extras
#define NPB 32         // nodes (=queries) per block
#define NBLK (MM/NPB)  // 1024 blocks for knn_conv1 / conv2
#define BPG (NBLK/NB)  // 128 conv2 blocks per graph
#define HROW 36        // h1s row stride (f32): 144B -> 16B-aligned, 2-way banks (free)
#define HALF 2048      // knn tile half size (points)

// Weight table offsets (floats)
#define OW1A 0
#define OB1A 128
#define OW1B 160
#define OB1B 1184
#define OW2A 1216
#define OB2A 2368
#define OW2B 2400
#define OB2B 3424
#define OWC  3456
#define OBC  4736
#define NWTS 4776

typedef short short8 __attribute__((ext_vector_type(8)));
typedef float f32x4  __attribute__((ext_vector_type(4)));
typedef float f32x2  __attribute__((ext_vector_type(2)));

// Module-global scratch (~21 MB): no assumptions about ws_size.
__device__ float4 g_pos4[MM];
__device__ float4 g_nrm4[MM];
__device__ int    g_nbr[MM*KK];
__device__ float  g_u[MM*CH];
__device__ float  g_wts[NWTS];
__device__ int    g_gmaxi[NB*CH];     // per-graph channel maxima (atomic, int-keyed f32>=0)
__device__ int    g_cnt[NB];          // per-graph done-counter (self-resetting)
__device__ __align__(16) float4 g_fe4[MM*SLOTS];   // PPF features cached conv1 -> conv2
// Pre-split (bf16 hi/lo) + pre-swizzled B-fragments for 16x16x32 MFMA:
// [ntile][hi/lo][lane][j] with value = W[k=(lane>>4)*8+j][n=ntile*16+(lane&15)]
__device__ __align__(16) unsigned short g_wfrag1[2][2][64][8];
__device__ __align__(16) unsigned short g_wfrag2[2][2][64][8];

__device__ __forceinline__ float bf(const __hip_bfloat16 x) { return __bfloat162float(x); }

__device__ __forceinline__ float ldf(const void* p, int i, bool f32) {
  return f32 ? ((const float*)p)[i] : bf(((const __hip_bfloat16*)p)[i]);
}

__device__ __forceinline__ float angf(float ax, float ay, float az,
                                      float bx, float by, float bz) {
  float cx = ay*bz - az*by;
  float cy = az*bx - ax*bz;
  float cz = ax*by - ay*bx;
  float s  = cx*cx + cy*cy + cz*cz;
  float cn = s > 0.f ? sqrtf(s) : 0.f;
  float d  = ax*bx + ay*by + az*bz;
  return (cn > 0.f || d != 0.f) ? atan2f(cn, d) : 0.f;
}

__device__ __forceinline__ void ppf4(const float4 pi, const float4 ni,
                                     const float4 pj, const float4 nj, float* f) {
  float px = pj.x - pi.x, py = pj.y - pi.y, pz = pj.z - pi.z;
  float s = px*px + py*py + pz*pz;
  f[0] = s > 0.f ? sqrtf(s) : 0.f;
  f[1] = angf(ni.x, ni.y, ni.z, px, py, pz);
  f[2] = angf(nj.x, nj.y, nj.z, px, py, pz);
  f[3] = angf(ni.x, ni.y, ni.z, nj.x, nj.y, nj.z);
}

__device__ __forceinline__ unsigned int mbcnt64(unsigned long long m) {
  return __builtin_amdgcn_mbcnt_hi((unsigned int)(m >> 32),
         __builtin_amdgcn_mbcnt_lo((unsigned int)m, 0u));
}

// split f32 -> bf16 hi/lo bit patterns
__device__ __forceinline__ void bsplit(float v, unsigned short* hi, unsigned short* lo) {
  __hip_bfloat16 h = __float2bfloat16(v);
  float hf = __bfloat162float(h);
  __hip_bfloat16 l = __float2bfloat16(v - hf);
  *hi = *reinterpret_cast<unsigned short*>(&h);
  *lo = *reinterpret_cast<unsigned short*>(&l);
}

// read 8 f32 from LDS row, split into hi/lo bf16 A-fragments (registers)
__device__ __forceinline__ void afrag(const float* row, short8* ah, short8* al) {
  float4 a = *(const float4*)row;
  float4 b = *(const float4*)(row + 4);
  unsigned short h, l;
  #pragma unroll
  for (int j = 0; j < 4; ++j) {
    bsplit((&a.x)[j], &h, &l); (*ah)[j]   = (short)h; (*al)[j]   = (short)l;
    bsplit((&b.x)[j], &h, &l); (*ah)[j+4] = (short)h; (*al)[j+4] = (short)l;
  }
}

// flat g_wts index -> source array element (for distributed weight conversion)
__device__ __forceinline__ float ldwt(int i, bool f32,
    const void* w1a, const void* b1a, const void* w1b, const void* b1b,
    const void* w2a, const void* b2a, const void* w2b, const void* b2b,
    const void* wc, const void* bc) {
  if (i < OB1A) return ldf(w1a, i - OW1A, f32);
  if (i < OW1B) return ldf(b1a, i - OB1A, f32);
  if (i < OB1B) return ldf(w1b, i - OW1B, f32);
  if (i < OW2A) return ldf(b1b, i - OB1B, f32);
  if (i < OB2A) return ldf(w2a, i - OW2A, f32);
  if (i < OW2B) return ldf(b2a, i - OB2A, f32);
  if (i < OB2B) return ldf(w2b, i - OW2B, f32);
  if (i < OWC)  return ldf(b2b, i - OB2B, f32);
  if (i < OBC)  return ldf(wc,  i - OWC,  f32);
  return ldf(bc, i - OBC, f32);
}

// ---------------- prep: dtype vote (per-block, same verdict) + inputs->float4.
// Weight work DISTRIBUTED: frag tables -> blocks 0-15; flat g_wts -> blocks 16-34.
__global__ __launch_bounds__(256) void prep_kernel(
    const void* __restrict__ pos, const void* __restrict__ nrm,
    const void* w1a, const void* b1a, const void* w1b, const void* b1b,
    const void* w2a, const void* b2a, const void* w2b, const void* b2b,
    const void* wc, const void* bc) {
  __shared__ int sflag;
  const int tid = threadIdx.x;
  const int bid = blockIdx.x;
  const int base = bid << 8;
  if (tid < 64) {                                   // wave 0: local dtype vote
    const float* nf = (const float*)nrm;
    const __hip_bfloat16* nh = (const __hip_bfloat16*)nrm;
    int n = base + tid;
    float x = nf[3*n], y = nf[3*n+1], z = nf[3*n+2];
    float ss = x*x + y*y + z*z;
    bool okf = (ss > 0.98f && ss < 1.02f);
    float a = bf(nh[3*n]), b2 = bf(nh[3*n+1]), c2 = bf(nh[3*n+2]);
    float sb = a*a + b2*b2 + c2*c2;
    bool okb = (sb > 0.95f && sb < 1.05f);
    unsigned long long mf = __ballot(okf), mb = __ballot(okb);
    if (tid == 0) sflag = (__popcll(mf) >= __popcll(mb)) ? 1 : 0;
  }
  __syncthreads();
  const bool f32 = sflag != 0;
  {
    int i = base + tid;
    float x = ldf(pos, 3*i, f32), y = ldf(pos, 3*i+1, f32), z = ldf(pos, 3*i+2, f32);
    g_pos4[i] = make_float4(x, y, z, x*x + y*y + z*z);
    float a = ldf(nrm, 3*i, f32), bb = ldf(nrm, 3*i+1, f32), cc = ldf(nrm, 3*i+2, f32);
    g_nrm4[i] = make_float4(a, bb, cc, 0.f);
  }
  if (bid < 16) {                                   // frag tables: 16 blocks x 256 entries
    int t = (bid << 8) + tid;
    int which = t >> 11;                 // 0 = w1b, 1 = w2b
    int r = t & 2047;
    int tt = r >> 10;  r &= 1023;
    int hl = r >> 9;   r &= 511;
    int ln = r >> 3;
    int j  = r & 7;
    int k = (ln >> 4)*8 + j;
    int c = tt*16 + (ln & 15);
    float wv = ldf(which ? w2b : w1b, k*CH + c, f32);
    unsigned short hi, lo;
    bsplit(wv, &hi, &lo);
    unsigned short v = hl ? lo : hi;
    if (which) g_wfrag2[tt][hl][ln][j] = v;
    else       g_wfrag1[tt][hl][ln][j] = v;
  } else if (bid < 35) {                            // g_wts: 19 blocks x 256 floats
    int i = ((bid - 16) << 8) + tid;
    if (i < NWTS)
      g_wts[i] = ldwt(i, f32, w1a, b1a, w1b, b1b, w2a, b2a, w2b, b2b, wc, bc);
  }
}

// ---------------- knn + conv1 fused: 1024 blocks x 512 thr, 32 q/block ------------------
// knn (R8): HALF-SAMPLE threshold -- min pass scans only half 0 (2048 cands, resident
// 24KB LDS tile). T = 17th-smallest lane-min via 64-lane f32 BITONIC SORT (exact, no
// ballots, no serial bisection chain). Invariant: T >= 17th-smallest d' in half 0
// >= d'17(full) since half subset of full => filter superset safe; survivors ~40 mean,
// CAP 96 overflow P ~ Phi(-8). Filter: half 0 first (resident, no re-stage), then
// stage+filter half 1 => 2 staging rounds total (was 3). Min/filter use bit-identical
// f32 arithmetic; margin bridges f32 d' to the exact-f64 ranking (unchanged).
// Ranking: 64-lane f64 bitonic (m<=64, ~all queries) or recompute fallback (m>64, rare).
// Natural VGPR (R3 lesson); LDS tile kept (R5 lesson: 8x L2-traffic suppressor).
__global__ __launch_bounds__(512) void knn_conv1_kernel() {
  __shared__ __align__(16) union SU {
    struct {
      float sx[HALF], sy[HALF], sz[HALF];           // 24576 B (half tile, SoA)
      unsigned short ilst[NPB][CAP];                //  6144 B
    } k;                                            // 30720 B
    struct {
      float fe[NPB*SLOTS][4];                       //  8704 B (544 edges)
      float h1s[152*HROW];                          // 21888 B (150 max row read + pad)
      float wsaT[32*HROW];                          //  4608 B (w2a[0:32] as [c][k])
      float xs[NPB][CH];                            //  4096 B
    } c;                                            // 39296 B
  } u;
  __shared__ unsigned short nbrs[NPB][KK];          //  1024 B (persists knn -> conv1)

  const int tid  = threadIdx.x;
  const int w    = tid >> 6, lane = tid & 63;
  const int blk  = blockIdx.x;
  const int b    = blk >> 7;                        // 128 blocks per batch
  const int qb   = (blk & 127) << 5;                // node base within batch
  const float4* bp = g_pos4 + b*NN;

  // query coefficients (global read; -2x is exact so x = -0.5*q2x recovers f32 coord)
  float q2x[4], q2y[4], q2z[4];
  #pragma unroll
  for (int qq = 0; qq < 4; ++qq) {
    float4 qv = bp[qb + (w << 2) + qq];
    q2x[qq] = -2.f*qv.x; q2y[qq] = -2.f*qv.y; q2z[qq] = -2.f*qv.z;
  }

  const f32x2* sx2 = (const f32x2*)u.k.sx;
  const f32x2* sy2 = (const f32x2*)u.k.sy;
  const f32x2* sz2 = (const f32x2*)u.k.sz;

  // ---- stage half 0; min pass over it: d' = |o|^2 - 2 q.o (shifted sq distance) ----
  #pragma unroll
  for (int k = 0; k < 4; ++k) {
    int idx = k*512 + tid;
    float4 o = bp[idx];
    u.k.sx[idx] = o.x; u.k.sy[idx] = o.y; u.k.sz[idx] = o.z;
  }
  __syncthreads();
  float mn[4];
  #pragma unroll
  for (int qq = 0; qq < 4; ++qq) mn[qq] = BIG;
  #pragma unroll 4
  for (int it = 0; it < 16; ++it) {
    int p = it*64 + lane;                           // pair index within half 0
    f32x2 ox = sx2[p], oy = sy2[p], oz = sz2[p];
    f32x2 ow = __builtin_elementwise_fma(oz, oz,
               __builtin_elementwise_fma(oy, oy, ox*ox));
    #pragma unroll
    for (int qq = 0; qq < 4; ++qq) {
      f32x2 qx = {q2x[qq], q2x[qq]};
      f32x2 qy = {q2y[qq], q2y[qq]};
      f32x2 qz = {q2z[qq], q2z[qq]};
      f32x2 d = __builtin_elementwise_fma(qx, ox,
                __builtin_elementwise_fma(qy, oy,
                __builtin_elementwise_fma(qz, oz, ow)));
      mn[qq] = fminf(fminf(d[0], d[1]), mn[qq]);    // -> v_min3_f32
    }
  }

  // ---- T via 64-lane f32 bitonic sort of lane-mins: sorted[16] = 17th smallest ----
  // >= 17 lanes (hence >= 17 half-0 candidates) have d' <= T => T >= d'17(full).
  float Tf[4];
  #pragma unroll
  for (int qq = 0; qq < 4; ++qq) {
    float v = mn[qq];
    #pragma unroll
    for (int k = 2; k <= 64; k <<= 1) {
      #pragma unroll
      for (int j = k >> 1; j >= 1; j >>= 1) {
        float pv = __shfl_xor(v, j);
        bool takeMin = (((lane & j) == 0) == ((lane & k) == 0));
        v = takeMin ? fminf(v, pv) : fmaxf(v, pv);
      }
    }
    float T = __shfl(v, 16);                        // exact 17th-smallest lane-min
    Tf[qq] = T + 4e-5f + 1e-5f*fabsf(T);            // margin bridges f32 d' -> f64 rank
  }

  // ---- filter pass: half 0 (resident) then half 1; ballot push, self INCLUDED ----
  unsigned int scnt[4];
  #pragma unroll
  for (int qq = 0; qq < 4; ++qq) scnt[qq] = 0u;
  #pragma unroll 1
  for (int h = 0; h < 2; ++h) {
    if (h == 1) {                                   // stage half 1
      __syncthreads();                              // all waves done reading half 0
      #pragma unroll
      for (int k = 0; k < 4; ++k) {
        int idx = k*512 + tid;
        float4 o = bp[HALF + idx];
        u.k.sx[idx] = o.x; u.k.sy[idx] = o.y; u.k.sz[idx] = o.z;
      }
      __syncthreads();
    }
    #pragma unroll 2
    for (int it = 0; it < 16; ++it) {
      int p = it*64 + lane;
      int gidx = h*HALF + 2*p;                      // global (in-batch) candidate idx
      f32x2 ox = sx2[p], oy = sy2[p], oz = sz2[p];
      f32x2 ow = __builtin_elementwise_fma(oz, oz,
                 __builtin_elementwise_fma(oy, oy, ox*ox));
      #pragma unroll
      for (int qq = 0; qq < 4; ++qq) {
        f32x2 qx = {q2x[qq], q2x[qq]};
        f32x2 qy = {q2y[qq], q2y[qq]};
        f32x2 qz = {q2z[qq], q2z[qq]};
        f32x2 d = __builtin_elementwise_fma(qx, ox,
                  __builtin_elementwise_fma(qy, oy,
                  __builtin_elementwise_fma(qz, oz, ow)));
        bool h0 = d[0] <= Tf[qq];
        bool h1 = d[1] <= Tf[qq];
        unsigned long long mk0 = __ballot(h0);
        unsigned long long mk1 = __ballot(h1);
        if (mk0 | mk1) {
          unsigned int cbase = scnt[qq];
          if (h0) {
            unsigned int pos = cbase + mbcnt64(mk0);
            if (pos < CAP) u.k.ilst[(w<<2)|qq][pos] = (unsigned short)gidx;
          }
          cbase += (unsigned int)__popcll(mk0);
          if (h1) {
            unsigned int pos = cbase + mbcnt64(mk1);
            if (pos < CAP) u.k.ilst[(w<<2)|qq][pos] = (unsigned short)(gidx + 1);
          }
          scnt[qq] = cbase + (unsigned int)__popcll(mk1);
        }
      }
    }
  }

  // ---- ranking: 64-lane bitonic sort by exact-f64 (d, idx); lane r = rank r ----
  #pragma unroll 1
  for (int qq = 0; qq < 4; ++qq) {
    const int ql = (w << 2) | qq;
    const int m = min((int)scnt[qq], CAP);
    const double mx = (double)(-0.5f*q2x[qq]);
    const double my_ = (double)(-0.5f*q2y[qq]);
    const double mz = (double)(-0.5f*q2z[qq]);
    const double sqme = (mx*mx + my_*my_) + mz*mz;
    if (m <= 64) {
      double d; int idx;
      if (lane < m) {
        int ci = u.k.ilst[ql][lane];
        float4 cv = bp[ci];
        double ox = (double)cv.x, oy = (double)cv.y, oz = (double)cv.z;
        double sqo = (ox*ox + oy*oy) + oz*oz;
        double dt  = (mx*ox + my_*oy) + mz*oz;
        d = (sqme + sqo) - 2.0*dt;
        idx = ci;
      } else { d = 1.0e300; idx = 0x7fffffff; }
      #pragma unroll
      for (int k = 2; k <= 64; k <<= 1) {
        #pragma unroll
        for (int j = k >> 1; j >= 1; j >>= 1) {
          double pd = __shfl_xor(d, j);
          int    pi = __shfl_xor(idx, j);
          bool mineLess = (d < pd) || (d == pd && idx < pi);
          bool wantMin  = (((lane & j) == 0) == ((lane & k) == 0));
          if (mineLess != wantMin) { d = pd; idx = pi; }
        }
      }
      if (lane >= 1 && lane <= KK) {                // rank 0 = self (exact d = 0)
        nbrs[ql][lane-1] = (unsigned short)idx;
        g_nbr[(b*NN + qb + ql)*KK + (lane-1)] = b*NN + idx;
      }
    } else {
      // cold fallback (64 < m <= CAP): recompute-based rank, global reads only
      for (int e = lane; e < m; e += 64) {
        int myi = u.k.ilst[ql][e];
        float4 cv = bp[myi];
        double ox = (double)cv.x, oy = (double)cv.y, oz = (double)cv.z;
        double myd = (sqme + ((ox*ox + oy*oy) + oz*oz))
                   - 2.0*((mx*ox + my_*oy) + mz*oz);
        int rank = 0;
        for (int o = 0; o < m; ++o) {
          int oi = u.k.ilst[ql][o];
          float4 ov = bp[oi];
          double px = (double)ov.x, py = (double)ov.y, pz = (double)ov.z;
          double od = (sqme + ((px*px + py*py) + pz*pz))
                    - 2.0*((mx*px + my_*py) + mz*pz);
          rank += (od < myd) || (od == myd && oi < myi);
        }
        if (rank >= 1 && rank <= KK) {
          nbrs[ql][rank-1] = (unsigned short)myi;
          g_nbr[(b*NN + qb + ql)*KK + (rank-1)] = b*NN + myi;
        }
      }
    }
  }

  // ---- conv1 phase (same block; no grid sync) ----
  const int c32 = tid & 31;
  const int quad = lane >> 4, l15 = lane & 15;
  float w1a_c[4];
  #pragma unroll
  for (int f = 0; f < 4; ++f) w1a_c[f] = g_wts[OW1A + f*CH + c32];
  const float b1a_c = g_wts[OB1A + c32];
  short8 bH0 = *(const short8*)&g_wfrag1[0][0][lane][0];
  short8 bL0 = *(const short8*)&g_wfrag1[0][1][lane][0];
  short8 bH1 = *(const short8*)&g_wfrag1[1][0][lane][0];
  short8 bL1 = *(const short8*)&g_wfrag1[1][1][lane][0];
  const float bias0 = g_wts[OB1B + l15];
  const float bias1 = g_wts[OB1B + 16 + l15];

  __syncthreads();                                  // union.k dead past this point

  for (int i2 = tid; i2 < 1024; i2 += 512) {        // stage w2a[0:32] transposed
    int k = i2 >> 5, cc = i2 & 31;
    u.c.wsaT[cc*HROW + k] = g_wts[OW2A + i2];
  }
  const int nbb = b*NN + qb;                        // global node base of this block
  for (int e = tid; e < NPB*SLOTS; e += 512) {      // 544 edges, balanced ppf staging
    int ns = e / 17, slot = e - ns*17;
    int ig = nbb + ns;
    int jg = (slot < KK) ? (b*NN + (int)nbrs[ns][slot]) : ig;  // slot 16 = self
    float f[4];
    ppf4(g_pos4[ig], g_nrm4[ig], g_pos4[jg], g_nrm4[jg], f);
    float4 fv = make_float4(f[0], f[1], f[2], f[3]);
    *(float4*)u.c.fe[e] = fv;
    g_fe4[(size_t)nbb*SLOTS + e] = fv;              // cache for conv2 (bit-identical)
  }
  __syncthreads();

  #pragma unroll 1
  for (int ck = 0; ck < 4; ++ck) {                  // 4 chunks x 8 nodes, 1 node/wave
    #pragma unroll
    for (int it = 0; it < 9; ++it) {                // h-phase: 136 rows x 32 ch
      int idx = it*512 + tid;
      int e = idx >> 5;                             // c == tid&31
      if (e < 136) {
        float4 f4 = *(const float4*)u.c.fe[ck*136 + e];
        float h = b1a_c + f4.x*w1a_c[0] + f4.y*w1a_c[1] + f4.z*w1a_c[2] + f4.w*w1a_c[3];
        u.c.h1s[e*HROW + c32] = fmaxf(h, 0.f);
      }
    }
    __syncthreads();
    {                                               // MFMA: wave w owns node ck*8+w
      const int rbase = w*17;
      short8 ah0, al0, ah1, al1;
      afrag(&u.c.h1s[(rbase      + l15)*HROW + quad*8], &ah0, &al0);
      afrag(&u.c.h1s[(rbase + 16 + l15)*HROW + quad*8], &ah1, &al1);
      f32x4 a00 = {0.f,0.f,0.f,0.f}, a01 = a00, a10 = a00, a11 = a00;
      a00 = __builtin_amdgcn_mfma_f32_16x16x32_bf16(ah0, bH0, a00, 0, 0, 0);
      a00 = __builtin_amdgcn_mfma_f32_16x16x32_bf16(ah0, bL0, a00, 0, 0, 0);
      a00 = __builtin_amdgcn_mfma_f32_16x16x32_bf16(al0, bH0, a00, 0, 0, 0);
      a01 = __builtin_amdgcn_mfma_f32_16x16x32_bf16(ah0, bH1, a01, 0, 0, 0);
      a01 = __builtin_amdgcn_mfma_f32_16x16x32_bf16(ah0, bL1, a01, 0, 0, 0);
      a01 = __builtin_amdgcn_mfma_f32_16x16x32_bf16(al0, bH1, a01, 0, 0, 0);
      a10 = __builtin_amdgcn_mfma_f32_16x16x32_bf16(ah1, bH0, a10, 0, 0, 0);
      a10 = __builtin_amdgcn_mfma_f32_16x16x32_bf16(ah1, bL0, a10, 0, 0, 0);
      a10 = __builtin_amdgcn_mfma_f32_16x16x32_bf16(al1, bH0, a10, 0, 0, 0);
      a11 = __builtin_amdgcn_mfma_f32_16x16x32_bf16(ah1, bH1, a11, 0, 0, 0);
      a11 = __builtin_amdgcn_mfma_f32_16x16x32_bf16(ah1, bL1, a11, 0, 0, 0);
      a11 = __builtin_amdgcn_mfma_f32_16x16x32_bf16(al1, bH1, a11, 0, 0, 0);
      float m0 = fmaxf(fmaxf(a00[0], a00[1]), fmaxf(a00[2], a00[3]));
      float m1 = fmaxf(fmaxf(a01[0], a01[1]), fmaxf(a01[2], a01[3]));
      if (quad == 0) { m0 = fmaxf(m0, a10[0]); m1 = fmaxf(m1, a11[0]); }
      m0 = fmaxf(m0, __shfl_xor(m0, 16)); m0 = fmaxf(m0, __shfl_xor(m0, 32));
      m1 = fmaxf(m1, __shfl_xor(m1, 16)); m1 = fmaxf(m1, __shfl_xor(m1, 32));
      if (quad == 0) {
        u.c.xs[ck*8 + w][l15]      = fmaxf(m0 + bias0, 0.f);  // x1 = relu(max + b1b)
        u.c.xs[ck*8 + w][16 + l15] = fmaxf(m1 + bias1, 0.f);
      }
    }
    __syncthreads();
  }
  #pragma unroll
  for (int it = 0; it < 2; ++it) {                  // u-epilogue: 32 nodes x 32 ch
    int ns = it*16 + (tid >> 5);
    float uu = 0.f;
    #pragma unroll
    for (int k4 = 0; k4 < 8; ++k4) {
      float4 x4 = *(const float4*)&u.c.xs[ns][4*k4];
      float4 w4 = *(const float4*)&u.c.wsaT[c32*HROW + 4*k4];
      uu += x4.x*w4.x + x4.y*w4.y + x4.z*w4.z + x4.w*w4.w;
    }
    g_u[(nbb + ns)*CH + c32] = uu;                  // u = x1 @ w2a[0:32,:]
  }
}

// ---------------- conv2 + fused head via device-scope ATOMICS (no fences on hot path) --
// g_u gather software-prefetched one chunk ahead into registers (R7, validated).
__global__ __launch_bounds__(512) void conv2_kernel(float* __restrict__ out) {
  __shared__ __align__(16) float fe[NPB*SLOTS][4];  //  8704 B
  __shared__ int jn[NPB*SLOTS];                     //  2176 B
  __shared__ __align__(16) float h1s[152*HROW];     // 21888 B
  __shared__ float xs[NPB][CH];                     //  4096 B
  __shared__ float gm2[CH];
  __shared__ int slast;
  const int tid = threadIdx.x;
  const int c = tid & 31;
  const int s16 = tid >> 5;                         // row-group 0..15
  const int lane = tid & 63, wv = tid >> 6;
  const int quad = lane >> 4, l15 = lane & 15;
  const int node0 = blockIdx.x << 5;                // 32 nodes/block
  const int g = blockIdx.x >> 7;                    // graph index (128 blocks/graph)
  float w2aL_c[4];
  #pragma unroll
  for (int f = 0; f < 4; ++f) w2aL_c[f] = g_wts[OW2A + (CH + f)*CH + c];
  const float b2a_c = g_wts[OB2A + c];
  short8 bH0 = *(const short8*)&g_wfrag2[0][0][lane][0];
  short8 bL0 = *(const short8*)&g_wfrag2[0][1][lane][0];
  short8 bH1 = *(const short8*)&g_wfrag2[1][0][lane][0];
  short8 bL1 = *(const short8*)&g_wfrag2[1][1][lane][0];
  const float bias0 = g_wts[OB2B + l15];
  const float bias1 = g_wts[OB2B + 16 + l15];

  for (int e = tid; e < NPB*SLOTS; e += 512) {      // stage jn + cached fe (coalesced)
    int ns = e / 17, slot = e - ns*17;
    int i = node0 + ns;
    jn[e] = (slot < KK) ? g_nbr[i*KK + slot] : i;
    *(float4*)fe[e] = g_fe4[(size_t)node0*SLOTS + e];
  }
  __syncthreads();

  float upf[9];                                     // u prefetch (chunk ahead)
  #pragma unroll
  for (int it = 0; it < 9; ++it) {                  // prefetch chunk 0
    int e = it*16 + s16;
    int ee = (e < 136) ? e : 135;                   // clamp (tail rows unused)
    upf[it] = g_u[jn[ee]*CH + c];
  }

  #pragma unroll 1
  for (int ck = 0; ck < 4; ++ck) {
    #pragma unroll
    for (int it = 0; it < 9; ++it) {                // h-phase: 136 rows x 32 ch
      int e = it*16 + s16;                          // == (it*512+tid)>>5
      if (e < 136) {
        float4 f4 = *(const float4*)fe[ck*136 + e];
        float h = b2a_c + upf[it] + f4.x*w2aL_c[0] + f4.y*w2aL_c[1]
                + f4.z*w2aL_c[2] + f4.w*w2aL_c[3];
        h1s[e*HROW + c] = fmaxf(h, 0.f);
      }
    }
    __syncthreads();
    if (ck < 3) {                                   // prefetch next chunk's u rows;
      #pragma unroll                                // in flight across the MFMA phase
      for (int it = 0; it < 9; ++it) {
        int e = it*16 + s16;
        int ee = (e < 136) ? e : 135;
        upf[it] = g_u[jn[(ck+1)*136 + ee]*CH + c];
      }
    }
    {                                               // MFMA: wave wv owns node ck*8+wv
      const int rbase = wv*17;
      short8 ah0, al0, ah1, al1;
      afrag(&h1s[(rbase      + l15)*HROW + quad*8], &ah0, &al0);
      afrag(&h1s[(rbase + 16 + l15)*HROW + quad*8], &ah1, &al1);
      f32x4 a00 = {0.f,0.f,0.f,0.f}, a01 = a00, a10 = a00, a11 = a00;
      a00 = __builtin_amdgcn_mfma_f32_16x16x32_bf16(ah0, bH0, a00, 0, 0, 0);
      a00 = __builtin_amdgcn_mfma_f32_16x16x32_bf16(ah0, bL0, a00, 0, 0, 0);
      a00 = __builtin_amdgcn_mfma_f32_16x16x32_bf16(al0, bH0, a00, 0, 0, 0);
      a01 = __builtin_amdgcn_mfma_f32_16x16x32_bf16(ah0, bH1, a01, 0, 0, 0);
      a01 = __builtin_amdgcn_mfma_f32_16x16x32_bf16(ah0, bL1, a01, 0, 0, 0);
      a01 = __builtin_amdgcn_mfma_f32_16x16x32_bf16(al0, bH1, a01, 0, 0, 0);
      a10 = __builtin_amdgcn_mfma_f32_16x16x32_bf16(ah1, bH0, a10, 0, 0, 0);
      a10 = __builtin_amdgcn_mfma_f32_16x16x32_bf16(ah1, bL0, a10, 0, 0, 0);
      a10 = __builtin_amdgcn_mfma_f32_16x16x32_bf16(al1, bH0, a10, 0, 0, 0);
      a11 = __builtin_amdgcn_mfma_f32_16x16x32_bf16(ah1, bH1, a11, 0, 0, 0);
      a11 = __builtin_amdgcn_mfma_f32_16x16x32_bf16(ah1, bL1, a11, 0, 0, 0);
      a11 = __builtin_amdgcn_mfma_f32_16x16x32_bf16(al1, bH1, a11, 0, 0, 0);
      float m0 = fmaxf(fmaxf(a00[0], a00[1]), fmaxf(a00[2], a00[3]));
      float m1 = fmaxf(fmaxf(a01[0], a01[1]), fmaxf(a01[2], a01[3]));
      if (quad == 0) { m0 = fmaxf(m0, a10[0]); m1 = fmaxf(m1, a11[0]); }
      m0 = fmaxf(m0, __shfl_xor(m0, 16)); m0 = fmaxf(m0, __shfl_xor(m0, 32));
      m1 = fmaxf(m1, __shfl_xor(m1, 16)); m1 = fmaxf(m1, __shfl_xor(m1, 32));
      if (quad == 0) {
        xs[ck*8 + wv][l15]      = fmaxf(m0 + bias0, 0.f);    // x2 = relu(max + b2b)
        xs[ck*8 + wv][16 + l15] = fmaxf(m1 + bias1, 0.f);
      }
    }
    __syncthreads();
  }
  if (tid < CH) {                                   // wave 0: block max -> atomic max
    float m2 = xs[0][c];
    #pragma unroll
    for (int r = 1; r < NPB; ++r) m2 = fmaxf(m2, xs[r][c]);
    int old = atomicMax(&g_gmaxi[g*CH + c], __float_as_int(m2));
    asm volatile("" :: "v"(old));                   // consume -> vmcnt wait -> performed
  }
  if (tid == 0) {                                   // same wave: maxes performed first
    int rank = atomicAdd(&g_cnt[g], 1);
    slast = (rank == BPG - 1) ? 1 : 0;
  }
  __syncthreads();
  if (slast) {                                      // last block of this graph: head
    __builtin_amdgcn_fence(__ATOMIC_ACQUIRE, "agent");   // one L2 inv per graph (8 total)
    if (tid < CH) gm2[c] = __int_as_float(((volatile int*)g_gmaxi)[g*CH + c]);
    __syncthreads();
    if (tid < NCLS) {
      float s = g_wts[OBC + tid];
      #pragma unroll
      for (int f = 0; f < CH; ++f) s += gm2[f] * g_wts[OWC + f*NCLS + tid];
      out[g*NCLS + tid] = s;                        // float32 out (reference dtype)
    }
    if (tid < CH) atomicExch(&g_gmaxi[g*CH + tid], 0);   // reset for graph replay
    if (tid == 0) atomicExch(&g_cnt[g], 0);
  }
}

extern "C" void kernel_launch(void* const* d_in, const int* in_sizes, int n_in,
                              void* d_out, int out_size, void* d_ws, size_t ws_size,
                              hipStream_t stream) {
  const void* pos = d_in[0];
  const void* nrm = d_in[1];
  // d_in[2] = batch (int32) -- unused, batches are uniform
  const void* w1a = d_in[3];
  const void* b1a = d_in[4];
  const void* w1b = d_in[5];
  const void* b1b = d_in[6];
  const void* w2a = d_in[7];
  const void* b2a = d_in[8];
  const void* w2b = d_in[9];
  const void* b2b = d_in[10];
  const void* wc  = d_in[11];
  const void* bc  = d_in[12];

  prep_kernel<<<MM/256, 256, 0, stream>>>(pos, nrm, w1a, b1a, w1b, b1b,
                                          w2a, b2a, w2b, b2b, wc, bc);
  knn_conv1_kernel<<<NBLK, 512, 0, stream>>>();
  conv2_kernel<<<NBLK, 512, 0, stream>>>((float*)d_out);
}

// Round 9
// 208.933 us; speedup vs baseline: 1.0374x; 1.0374x over previous
//
#include <hip/hip_runtime.h>
#include <hip/hip_bf16.h>
#include <math.h>

#define NB 8
#define NN 4096
#define KK 16
#define MM (NB*NN)
#define CH 32
#define SLOTS 17
#define NCLS 40
#define BIG 3.0e38f
#define CAP 96         // survivors ~25-27 incl. self; ballot-push drops extras safely
#define NPB 32         // knn_conv1 nodes/block
#define NBLK (MM/NPB)  // 1024 blocks for knn_conv1
#define NPB2 16        // conv2 nodes/block (256 threads, 8 blocks/CU)
#define NBLK2 (MM/NPB2) // 2048 conv2 blocks
#define BPG2 (NBLK2/NB) // 256 conv2 blocks per graph
#define CK2 4          // conv2 nodes per chunk
#define ROWS2 (CK2*SLOTS)  // 68 rows per chunk
#define H1R2 88        // h1s rows allocated (max read 82 + pad)
#define HROW 36        // h1s row stride (f32): 144B -> 16B-aligned, 2-way banks (free)
#define HALF 2048      // knn tile half size (points)

// Weight table offsets (floats)
#define OW1A 0
#define OB1A 128
#define OW1B 160
#define OB1B 1184
#define OW2A 1216
#define OB2A 2368
#define OW2B 2400
#define OB2B 3424
#define OWC  3456
#define OBC  4736
#define NWTS 4776

typedef short short8 __attribute__((ext_vector_type(8)));
typedef float f32x4  __attribute__((ext_vector_type(4)));
typedef float f32x2  __attribute__((ext_vector_type(2)));

// Module-global scratch (~21 MB): no assumptions about ws_size.
__device__ float4 g_pos4[MM];
__device__ float4 g_nrm4[MM];
__device__ int    g_nbr[MM*KK];
__device__ float  g_u[MM*CH];
__device__ float  g_wts[NWTS];
__device__ int    g_gmaxi[NB*CH];     // per-graph channel maxima (atomic, int-keyed f32>=0)
__device__ int    g_cnt[NB];          // per-graph done-counter (self-resetting)
__device__ __align__(16) float4 g_fe4[MM*SLOTS];   // PPF features cached conv1 -> conv2
// Pre-split (bf16 hi/lo) + pre-swizzled B-fragments for 16x16x32 MFMA:
// [ntile][hi/lo][lane][j] with value = W[k=(lane>>4)*8+j][n=ntile*16+(lane&15)]
__device__ __align__(16) unsigned short g_wfrag1[2][2][64][8];
__device__ __align__(16) unsigned short g_wfrag2[2][2][64][8];

__device__ __forceinline__ float bf(const __hip_bfloat16 x) { return __bfloat162float(x); }

__device__ __forceinline__ float ldf(const void* p, int i, bool f32) {
  return f32 ? ((const float*)p)[i] : bf(((const __hip_bfloat16*)p)[i]);
}

__device__ __forceinline__ float angf(float ax, float ay, float az,
                                      float bx, float by, float bz) {
  float cx = ay*bz - az*by;
  float cy = az*bx - ax*bz;
  float cz = ax*by - ay*bx;
  float s  = cx*cx + cy*cy + cz*cz;
  float cn = s > 0.f ? sqrtf(s) : 0.f;
  float d  = ax*bx + ay*by + az*bz;
  return (cn > 0.f || d != 0.f) ? atan2f(cn, d) : 0.f;
}

__device__ __forceinline__ void ppf4(const float4 pi, const float4 ni,
                                     const float4 pj, const float4 nj, float* f) {
  float px = pj.x - pi.x, py = pj.y - pi.y, pz = pj.z - pi.z;
  float s = px*px + py*py + pz*pz;
  f[0] = s > 0.f ? sqrtf(s) : 0.f;
  f[1] = angf(ni.x, ni.y, ni.z, px, py, pz);
  f[2] = angf(nj.x, nj.y, nj.z, px, py, pz);
  f[3] = angf(ni.x, ni.y, ni.z, nj.x, nj.y, nj.z);
}

// monotone f32 -> u32 key (order-preserving for all finite floats)
__device__ __forceinline__ unsigned int fkey(float f) {
  unsigned int u = __float_as_uint(f);
  return (u & 0x80000000u) ? ~u : (u | 0x80000000u);
}
__device__ __forceinline__ float funkey(unsigned int k) {
  unsigned int u = (k & 0x80000000u) ? (k ^ 0x80000000u) : ~k;
  return __uint_as_float(u);
}

__device__ __forceinline__ unsigned int mbcnt64(unsigned long long m) {
  return __builtin_amdgcn_mbcnt_hi((unsigned int)(m >> 32),
         __builtin_amdgcn_mbcnt_lo((unsigned int)m, 0u));
}

// split f32 -> bf16 hi/lo bit patterns
__device__ __forceinline__ void bsplit(float v, unsigned short* hi, unsigned short* lo) {
  __hip_bfloat16 h = __float2bfloat16(v);
  float hf = __bfloat162float(h);
  __hip_bfloat16 l = __float2bfloat16(v - hf);
  *hi = *reinterpret_cast<unsigned short*>(&h);
  *lo = *reinterpret_cast<unsigned short*>(&l);
}

// read 8 f32 from LDS row, split into hi/lo bf16 A-fragments (registers)
__device__ __forceinline__ void afrag(const float* row, short8* ah, short8* al) {
  float4 a = *(const float4*)row;
  float4 b = *(const float4*)(row + 4);
  unsigned short h, l;
  #pragma unroll
  for (int j = 0; j < 4; ++j) {
    bsplit((&a.x)[j], &h, &l); (*ah)[j]   = (short)h; (*al)[j]   = (short)l;
    bsplit((&b.x)[j], &h, &l); (*ah)[j+4] = (short)h; (*al)[j+4] = (short)l;
  }
}

// flat g_wts index -> source array element (for distributed weight conversion)
__device__ __forceinline__ float ldwt(int i, bool f32,
    const void* w1a, const void* b1a, const void* w1b, const void* b1b,
    const void* w2a, const void* b2a, const void* w2b, const void* b2b,
    const void* wc, const void* bc) {
  if (i < OB1A) return ldf(w1a, i - OW1A, f32);
  if (i < OW1B) return ldf(b1a, i - OB1A, f32);
  if (i < OB1B) return ldf(w1b, i - OW1B, f32);
  if (i < OW2A) return ldf(b1b, i - OB1B, f32);
  if (i < OB2A) return ldf(w2a, i - OW2A, f32);
  if (i < OW2B) return ldf(b2a, i - OB2A, f32);
  if (i < OB2B) return ldf(w2b, i - OW2B, f32);
  if (i < OWC)  return ldf(b2b, i - OB2B, f32);
  if (i < OBC)  return ldf(wc,  i - OWC,  f32);
  return ldf(bc, i - OBC, f32);
}

// ---------------- prep: dtype vote (per-block, same verdict) + inputs->float4.
// Weight work DISTRIBUTED: frag tables -> blocks 0-15; flat g_wts -> blocks 16-34.
__global__ __launch_bounds__(256) void prep_kernel(
    const void* __restrict__ pos, const void* __restrict__ nrm,
    const void* w1a, const void* b1a, const void* w1b, const void* b1b,
    const void* w2a, const void* b2a, const void* w2b, const void* b2b,
    const void* wc, const void* bc) {
  __shared__ int sflag;
  const int tid = threadIdx.x;
  const int bid = blockIdx.x;
  const int base = bid << 8;
  if (tid < 64) {                                   // wave 0: local dtype vote
    const float* nf = (const float*)nrm;
    const __hip_bfloat16* nh = (const __hip_bfloat16*)nrm;
    int n = base + tid;
    float x = nf[3*n], y = nf[3*n+1], z = nf[3*n+2];
    float ss = x*x + y*y + z*z;
    bool okf = (ss > 0.98f && ss < 1.02f);
    float a = bf(nh[3*n]), b2 = bf(nh[3*n+1]), c2 = bf(nh[3*n+2]);
    float sb = a*a + b2*b2 + c2*c2;
    bool okb = (sb > 0.95f && sb < 1.05f);
    unsigned long long mf = __ballot(okf), mb = __ballot(okb);
    if (tid == 0) sflag = (__popcll(mf) >= __popcll(mb)) ? 1 : 0;
  }
  __syncthreads();
  const bool f32 = sflag != 0;
  {
    int i = base + tid;
    float x = ldf(pos, 3*i, f32), y = ldf(pos, 3*i+1, f32), z = ldf(pos, 3*i+2, f32);
    g_pos4[i] = make_float4(x, y, z, x*x + y*y + z*z);
    float a = ldf(nrm, 3*i, f32), bb = ldf(nrm, 3*i+1, f32), cc = ldf(nrm, 3*i+2, f32);
    g_nrm4[i] = make_float4(a, bb, cc, 0.f);
  }
  if (bid < 16) {                                   // frag tables: 16 blocks x 256 entries
    int t = (bid << 8) + tid;
    int which = t >> 11;                 // 0 = w1b, 1 = w2b
    int r = t & 2047;
    int tt = r >> 10;  r &= 1023;
    int hl = r >> 9;   r &= 511;
    int ln = r >> 3;
    int j  = r & 7;
    int k = (ln >> 4)*8 + j;
    int c = tt*16 + (ln & 15);
    float wv = ldf(which ? w2b : w1b, k*CH + c, f32);
    unsigned short hi, lo;
    bsplit(wv, &hi, &lo);
    unsigned short v = hl ? lo : hi;
    if (which) g_wfrag2[tt][hl][ln][j] = v;
    else       g_wfrag1[tt][hl][ln][j] = v;
  } else if (bid < 35) {                            // g_wts: 19 blocks x 256 floats
    int i = ((bid - 16) << 8) + tid;
    if (i < NWTS)
      g_wts[i] = ldwt(i, f32, w1a, b1a, w1b, b1b, w2a, b2a, w2b, b2b, wc, bc);
  }
}

// ---------------- knn + conv1 fused: 1024 blocks x 512 thr, 32 q/block ------------------
// R7 version verbatim (measured 103.0 us; R8's half-sample/bitonic-T experiment
// regressed +21 us and was reverted). knn: 2-half LDS tile (24KB, 8x L2-traffic
// suppressor); packed-pair distances; 16-step bisection on 16-bit keys; ballot push
// (no atomics, self-loop included -> exact-f64 rank 0, neighbors ranks 1..16); filter
// processes half 1 first (resident). Ranking: 64-lane f64 bitonic (shuffle-only) with
// recompute fallback for m>64. Natural VGPR (R3 lesson: forced occupancy -> spills).
__global__ __launch_bounds__(512) void knn_conv1_kernel() {
  __shared__ __align__(16) union SU {
    struct {
      float sx[HALF], sy[HALF], sz[HALF];           // 24576 B (half tile, SoA)
      unsigned short ilst[NPB][CAP];                //  6144 B
    } k;                                            // 30720 B
    struct {
      float fe[NPB*SLOTS][4];                       //  8704 B (544 edges)
      float h1s[152*HROW];                          // 21888 B (150 max row read + pad)
      float wsaT[32*HROW];                          //  4608 B (w2a[0:32] as [c][k])
      float xs[NPB][CH];                            //  4096 B
    } c;                                            // 39296 B
  } u;
  __shared__ unsigned short nbrs[NPB][KK];          //  1024 B (persists knn -> conv1)

  const int tid  = threadIdx.x;
  const int w    = tid >> 6, lane = tid & 63;
  const int blk  = blockIdx.x;
  const int b    = blk >> 7;                        // 128 blocks per batch
  const int qb   = (blk & 127) << 5;                // node base within batch
  const float4* bp = g_pos4 + b*NN;

  // query coefficients (global read; -2x is exact so x = -0.5*q2x recovers f32 coord)
  float q2x[4], q2y[4], q2z[4];
  #pragma unroll
  for (int qq = 0; qq < 4; ++qq) {
    float4 qv = bp[qb + (w << 2) + qq];
    q2x[qq] = -2.f*qv.x; q2y[qq] = -2.f*qv.y; q2z[qq] = -2.f*qv.z;
  }

  const f32x2* sx2 = (const f32x2*)u.k.sx;
  const f32x2* sy2 = (const f32x2*)u.k.sy;
  const f32x2* sz2 = (const f32x2*)u.k.sz;

  // ---- min pass over halves {0,1}: d' = |o|^2 - 2 q.o (shifted squared distance) ----
  float mn[4];
  #pragma unroll
  for (int qq = 0; qq < 4; ++qq) mn[qq] = BIG;
  #pragma unroll 1
  for (int h = 0; h < 2; ++h) {
    #pragma unroll
    for (int k = 0; k < 4; ++k) {                   // stage half (32KB global -> 24KB LDS)
      int idx = k*512 + tid;
      float4 o = bp[h*HALF + idx];
      u.k.sx[idx] = o.x; u.k.sy[idx] = o.y; u.k.sz[idx] = o.z;
    }
    __syncthreads();
    #pragma unroll 4
    for (int it = 0; it < 16; ++it) {
      int p = it*64 + lane;                         // pair index within half
      f32x2 ox = sx2[p], oy = sy2[p], oz = sz2[p];
      f32x2 ow = __builtin_elementwise_fma(oz, oz,
                 __builtin_elementwise_fma(oy, oy, ox*ox));
      #pragma unroll
      for (int qq = 0; qq < 4; ++qq) {
        f32x2 qx = {q2x[qq], q2x[qq]};
        f32x2 qy = {q2y[qq], q2y[qq]};
        f32x2 qz = {q2z[qq], q2z[qq]};
        f32x2 d = __builtin_elementwise_fma(qx, ox,
                  __builtin_elementwise_fma(qy, oy,
                  __builtin_elementwise_fma(qz, oz, ow)));
        mn[qq] = fminf(fminf(d[0], d[1]), mn[qq]);  // -> v_min3_f32
      }
    }
    if (h == 0) __syncthreads();                    // half reads done before re-stage
  }

  // ---- 16-step bisection over 16-bit truncated keys (threshold bucket rounded UP).
  // Invariant (any candidate->lane mapping): minimal bucket T with >=17 lane-mins <= T
  // => >=17 candidates <= T => d17 <= T => filter superset is safe.
  unsigned int key[4], lo[4], hi[4];
  #pragma unroll
  for (int qq = 0; qq < 4; ++qq) { key[qq] = fkey(mn[qq]) >> 16; lo[qq] = 0u; hi[qq] = 0xFFFFu; }
  #pragma unroll 1
  for (int s = 0; s < 16; ++s) {
    #pragma unroll
    for (int qq = 0; qq < 4; ++qq) {
      unsigned int mid = (lo[qq] + hi[qq]) >> 1;
      int c = (int)__popcll(__ballot(key[qq] <= mid));
      if (c >= 17) hi[qq] = mid; else lo[qq] = mid + 1;
    }
  }
  float Tf[4];
  #pragma unroll
  for (int qq = 0; qq < 4; ++qq) {
    float T = funkey((hi[qq] << 16) | 0xFFFFu);     // >= exact 17th smallest (incl self)
    Tf[qq] = T + 4e-5f + 1e-5f*fabsf(T);            // margin >> f32 d' abs error
  }

  // ---- filter pass, halves {1, 0}: half 1 is still resident -> no re-stage ----
  unsigned int scnt[4];
  #pragma unroll
  for (int qq = 0; qq < 4; ++qq) scnt[qq] = 0u;
  #pragma unroll 1
  for (int hh = 0; hh < 2; ++hh) {
    const int h = 1 - hh;                           // process resident half first
    if (hh == 1) {                                  // re-stage half 0
      __syncthreads();                              // all waves done reading half 1
      #pragma unroll
      for (int k = 0; k < 4; ++k) {
        int idx = k*512 + tid;
        float4 o = bp[h*HALF + idx];
        u.k.sx[idx] = o.x; u.k.sy[idx] = o.y; u.k.sz[idx] = o.z;
      }
      __syncthreads();
    }
    #pragma unroll 2
    for (int it = 0; it < 16; ++it) {
      int p = it*64 + lane;
      int gidx = h*HALF + 2*p;                      // global (in-batch) candidate idx
      f32x2 ox = sx2[p], oy = sy2[p], oz = sz2[p];
      f32x2 ow = __builtin_elementwise_fma(oz, oz,
                 __builtin_elementwise_fma(oy, oy, ox*ox));
      #pragma unroll
      for (int qq = 0; qq < 4; ++qq) {
        f32x2 qx = {q2x[qq], q2x[qq]};
        f32x2 qy = {q2y[qq], q2y[qq]};
        f32x2 qz = {q2z[qq], q2z[qq]};
        f32x2 d = __builtin_elementwise_fma(qx, ox,
                  __builtin_elementwise_fma(qy, oy,
                  __builtin_elementwise_fma(qz, oz, ow)));
        bool h0 = d[0] <= Tf[qq];
        bool h1 = d[1] <= Tf[qq];
        unsigned long long mk0 = __ballot(h0);
        unsigned long long mk1 = __ballot(h1);
        if (mk0 | mk1) {
          unsigned int cbase = scnt[qq];
          if (h0) {
            unsigned int pos = cbase + mbcnt64(mk0);
            if (pos < CAP) u.k.ilst[(w<<2)|qq][pos] = (unsigned short)gidx;
          }
          cbase += (unsigned int)__popcll(mk0);
          if (h1) {
            unsigned int pos = cbase + mbcnt64(mk1);
            if (pos < CAP) u.k.ilst[(w<<2)|qq][pos] = (unsigned short)(gidx + 1);
          }
          scnt[qq] = cbase + (unsigned int)__popcll(mk1);
        }
      }
    }
  }

  // ---- ranking: 64-lane bitonic sort by exact-f64 (d, idx); lane r = rank r ----
  #pragma unroll 1
  for (int qq = 0; qq < 4; ++qq) {
    const int ql = (w << 2) | qq;
    const int m = min((int)scnt[qq], CAP);
    const double mx = (double)(-0.5f*q2x[qq]);
    const double my_ = (double)(-0.5f*q2y[qq]);
    const double mz = (double)(-0.5f*q2z[qq]);
    const double sqme = (mx*mx + my_*my_) + mz*mz;
    if (m <= 64) {
      double d; int idx;
      if (lane < m) {
        int ci = u.k.ilst[ql][lane];
        float4 cv = bp[ci];
        double ox = (double)cv.x, oy = (double)cv.y, oz = (double)cv.z;
        double sqo = (ox*ox + oy*oy) + oz*oz;
        double dt  = (mx*ox + my_*oy) + mz*oz;
        d = (sqme + sqo) - 2.0*dt;
        idx = ci;
      } else { d = 1.0e300; idx = 0x7fffffff; }
      #pragma unroll
      for (int k = 2; k <= 64; k <<= 1) {
        #pragma unroll
        for (int j = k >> 1; j >= 1; j >>= 1) {
          double pd = __shfl_xor(d, j);
          int    pi = __shfl_xor(idx, j);
          bool mineLess = (d < pd) || (d == pd && idx < pi);
          bool wantMin  = (((lane & j) == 0) == ((lane & k) == 0));
          if (mineLess != wantMin) { d = pd; idx = pi; }
        }
      }
      if (lane >= 1 && lane <= KK) {                // rank 0 = self (exact d = 0)
        nbrs[ql][lane-1] = (unsigned short)idx;
        g_nbr[(b*NN + qb + ql)*KK + (lane-1)] = b*NN + idx;
      }
    } else {
      // cold fallback (64 < m <= CAP): recompute-based rank, global reads only
      for (int e = lane; e < m; e += 64) {
        int myi = u.k.ilst[ql][e];
        float4 cv = bp[myi];
        double ox = (double)cv.x, oy = (double)cv.y, oz = (double)cv.z;
        double myd = (sqme + ((ox*ox + oy*oy) + oz*oz))
                   - 2.0*((mx*ox + my_*oy) + mz*oz);
        int rank = 0;
        for (int o = 0; o < m; ++o) {
          int oi = u.k.ilst[ql][o];
          float4 ov = bp[oi];
          double px = (double)ov.x, py = (double)ov.y, pz = (double)ov.z;
          double od = (sqme + ((px*px + py*py) + pz*pz))
                    - 2.0*((mx*px + my_*py) + mz*pz);
          rank += (od < myd) || (od == myd && oi < myi);
        }
        if (rank >= 1 && rank <= KK) {
          nbrs[ql][rank-1] = (unsigned short)myi;
          g_nbr[(b*NN + qb + ql)*KK + (rank-1)] = b*NN + myi;
        }
      }
    }
  }

  // ---- conv1 phase (same block; no grid sync) ----
  const int c32 = tid & 31;
  const int quad = lane >> 4, l15 = lane & 15;
  float w1a_c[4];
  #pragma unroll
  for (int f = 0; f < 4; ++f) w1a_c[f] = g_wts[OW1A + f*CH + c32];
  const float b1a_c = g_wts[OB1A + c32];
  short8 bH0 = *(const short8*)&g_wfrag1[0][0][lane][0];
  short8 bL0 = *(const short8*)&g_wfrag1[0][1][lane][0];
  short8 bH1 = *(const short8*)&g_wfrag1[1][0][lane][0];
  short8 bL1 = *(const short8*)&g_wfrag1[1][1][lane][0];
  const float bias0 = g_wts[OB1B + l15];
  const float bias1 = g_wts[OB1B + 16 + l15];

  __syncthreads();                                  // union.k dead past this point

  for (int i2 = tid; i2 < 1024; i2 += 512) {        // stage w2a[0:32] transposed
    int k = i2 >> 5, cc = i2 & 31;
    u.c.wsaT[cc*HROW + k] = g_wts[OW2A + i2];
  }
  const int nbb = b*NN + qb;                        // global node base of this block
  for (int e = tid; e < NPB*SLOTS; e += 512) {      // 544 edges, balanced ppf staging
    int ns = e / 17, slot = e - ns*17;
    int ig = nbb + ns;
    int jg = (slot < KK) ? (b*NN + (int)nbrs[ns][slot]) : ig;  // slot 16 = self
    float f[4];
    ppf4(g_pos4[ig], g_nrm4[ig], g_pos4[jg], g_nrm4[jg], f);
    float4 fv = make_float4(f[0], f[1], f[2], f[3]);
    *(float4*)u.c.fe[e] = fv;
    g_fe4[(size_t)nbb*SLOTS + e] = fv;              // cache for conv2 (bit-identical)
  }
  __syncthreads();

  #pragma unroll 1
  for (int ck = 0; ck < 4; ++ck) {                  // 4 chunks x 8 nodes, 1 node/wave
    #pragma unroll
    for (int it = 0; it < 9; ++it) {                // h-phase: 136 rows x 32 ch
      int idx = it*512 + tid;
      int e = idx >> 5;                             // c == tid&31
      if (e < 136) {
        float4 f4 = *(const float4*)u.c.fe[ck*136 + e];
        float h = b1a_c + f4.x*w1a_c[0] + f4.y*w1a_c[1] + f4.z*w1a_c[2] + f4.w*w1a_c[3];
        u.c.h1s[e*HROW + c32] = fmaxf(h, 0.f);
      }
    }
    __syncthreads();
    {                                               // MFMA: wave w owns node ck*8+w
      const int rbase = w*17;
      short8 ah0, al0, ah1, al1;
      afrag(&u.c.h1s[(rbase      + l15)*HROW + quad*8], &ah0, &al0);
      afrag(&u.c.h1s[(rbase + 16 + l15)*HROW + quad*8], &ah1, &al1);
      f32x4 a00 = {0.f,0.f,0.f,0.f}, a01 = a00, a10 = a00, a11 = a00;
      a00 = __builtin_amdgcn_mfma_f32_16x16x32_bf16(ah0, bH0, a00, 0, 0, 0);
      a00 = __builtin_amdgcn_mfma_f32_16x16x32_bf16(ah0, bL0, a00, 0, 0, 0);
      a00 = __builtin_amdgcn_mfma_f32_16x16x32_bf16(al0, bH0, a00, 0, 0, 0);
      a01 = __builtin_amdgcn_mfma_f32_16x16x32_bf16(ah0, bH1, a01, 0, 0, 0);
      a01 = __builtin_amdgcn_mfma_f32_16x16x32_bf16(ah0, bL1, a01, 0, 0, 0);
      a01 = __builtin_amdgcn_mfma_f32_16x16x32_bf16(al0, bH1, a01, 0, 0, 0);
      a10 = __builtin_amdgcn_mfma_f32_16x16x32_bf16(ah1, bH0, a10, 0, 0, 0);
      a10 = __builtin_amdgcn_mfma_f32_16x16x32_bf16(ah1, bL0, a10, 0, 0, 0);
      a10 = __builtin_amdgcn_mfma_f32_16x16x32_bf16(al1, bH0, a10, 0, 0, 0);
      a11 = __builtin_amdgcn_mfma_f32_16x16x32_bf16(ah1, bH1, a11, 0, 0, 0);
      a11 = __builtin_amdgcn_mfma_f32_16x16x32_bf16(ah1, bL1, a11, 0, 0, 0);
      a11 = __builtin_amdgcn_mfma_f32_16x16x32_bf16(al1, bH1, a11, 0, 0, 0);
      float m0 = fmaxf(fmaxf(a00[0], a00[1]), fmaxf(a00[2], a00[3]));
      float m1 = fmaxf(fmaxf(a01[0], a01[1]), fmaxf(a01[2], a01[3]));
      if (quad == 0) { m0 = fmaxf(m0, a10[0]); m1 = fmaxf(m1, a11[0]); }
      m0 = fmaxf(m0, __shfl_xor(m0, 16)); m0 = fmaxf(m0, __shfl_xor(m0, 32));
      m1 = fmaxf(m1, __shfl_xor(m1, 16)); m1 = fmaxf(m1, __shfl_xor(m1, 32));
      if (quad == 0) {
        u.c.xs[ck*8 + w][l15]      = fmaxf(m0 + bias0, 0.f);  // x1 = relu(max + b1b)
        u.c.xs[ck*8 + w][16 + l15] = fmaxf(m1 + bias1, 0.f);
      }
    }
    __syncthreads();
  }
  #pragma unroll
  for (int it = 0; it < 2; ++it) {                  // u-epilogue: 32 nodes x 32 ch
    int ns = it*16 + (tid >> 5);
    float uu = 0.f;
    #pragma unroll
    for (int k4 = 0; k4 < 8; ++k4) {
      float4 x4 = *(const float4*)&u.c.xs[ns][4*k4];
      float4 w4 = *(const float4*)&u.c.wsaT[c32*HROW + 4*k4];
      uu += x4.x*w4.x + x4.y*w4.y + x4.z*w4.z + x4.w*w4.w;
    }
    g_u[(nbb + ns)*CH + c32] = uu;                  // u = x1 @ w2a[0:32,:]
  }
}

// ---------------- conv2 + fused head: 256-thr / 16-node blocks (R9 restructure) --------
// 2048 blocks x 256 thr, LDS ~19.8KB -> 8 blocks/CU (32 waves from 8 INDEPENDENT blocks:
// barrier groups half as wide, 2x more blocks interleaving per CU vs 512-thr/4-block).
// 4 chunks x 4 nodes, 1 node/wave; u-gather prefetched one chunk ahead (R7, validated).
// MFMA garbage-row logic unchanged: wave reads rows up to rbase+31 = 82 < 88 allocated;
// garbage pollutes only discarded accumulator rows (per-row independence of MFMA).
// Head via device-scope atomicMax (R5, validated): no fences on hot path.
__global__ __launch_bounds__(256) void conv2_kernel(float* __restrict__ out) {
  __shared__ __align__(16) float fe[NPB2*SLOTS][4]; //  4352 B (272 edges)
  __shared__ unsigned short jn[NPB2*SLOTS];         //   544 B (node ids < 32768 -> u16)
  __shared__ __align__(16) float h1s[H1R2*HROW];    // 12672 B
  __shared__ float xs[NPB2][CH];                    //  2048 B
  __shared__ float gm2[CH];
  __shared__ int slast;                             // ~19.8 KB total -> 8 blocks/CU
  const int tid = threadIdx.x;
  const int c = tid & 31;
  const int s8 = tid >> 5;                          // row-group 0..7
  const int lane = tid & 63, wv = tid >> 6;         // wv 0..3
  const int quad = lane >> 4, l15 = lane & 15;
  const int node0 = blockIdx.x << 4;                // 16 nodes/block
  const int g = blockIdx.x >> 8;                    // graph index (256 blocks/graph)
  float w2aL_c[4];
  #pragma unroll
  for (int f = 0; f < 4; ++f) w2aL_c[f] = g_wts[OW2A + (CH + f)*CH + c];
  const float b2a_c = g_wts[OB2A + c];
  short8 bH0 = *(const short8*)&g_wfrag2[0][0][lane][0];
  short8 bL0 = *(const short8*)&g_wfrag2[0][1][lane][0];
  short8 bH1 = *(const short8*)&g_wfrag2[1][0][lane][0];
  short8 bL1 = *(const short8*)&g_wfrag2[1][1][lane][0];
  const float bias0 = g_wts[OB2B + l15];
  const float bias1 = g_wts[OB2B + 16 + l15];

  for (int e = tid; e < NPB2*SLOTS; e += 256) {     // stage jn + cached fe (coalesced)
    int ns = e / 17, slot = e - ns*17;
    int i = node0 + ns;
    jn[e] = (unsigned short)((slot < KK) ? g_nbr[i*KK + slot] : i);
    *(float4*)fe[e] = g_fe4[(size_t)node0*SLOTS + e];
  }
  __syncthreads();

  float upf[9];                                     // u prefetch (chunk ahead)
  #pragma unroll
  for (int it = 0; it < 9; ++it) {                  // prefetch chunk 0
    int e = it*8 + s8;
    int ee = (e < ROWS2) ? e : (ROWS2 - 1);         // clamp (tail rows unused)
    upf[it] = g_u[(int)jn[ee]*CH + c];
  }

  #pragma unroll 1
  for (int ck = 0; ck < 4; ++ck) {
    #pragma unroll
    for (int it = 0; it < 9; ++it) {                // h-phase: 68 rows x 32 ch
      int e = it*8 + s8;
      if (e < ROWS2) {
        float4 f4 = *(const float4*)fe[ck*ROWS2 + e];
        float h = b2a_c + upf[it] + f4.x*w2aL_c[0] + f4.y*w2aL_c[1]
                + f4.z*w2aL_c[2] + f4.w*w2aL_c[3];
        h1s[e*HROW + c] = fmaxf(h, 0.f);
      }
    }
    __syncthreads();
    if (ck < 3) {                                   // prefetch next chunk's u rows;
      #pragma unroll                                // in flight across the MFMA phase
      for (int it = 0; it < 9; ++it) {
        int e = it*8 + s8;
        int ee = (e < ROWS2) ? e : (ROWS2 - 1);
        upf[it] = g_u[(int)jn[(ck+1)*ROWS2 + ee]*CH + c];
      }
    }
    {                                               // MFMA: wave wv owns node ck*4+wv
      const int rbase = wv*17;                      // 0,17,34,51; reads <= row 82 < 88
      short8 ah0, al0, ah1, al1;
      afrag(&h1s[(rbase      + l15)*HROW + quad*8], &ah0, &al0);
      afrag(&h1s[(rbase + 16 + l15)*HROW + quad*8], &ah1, &al1);
      f32x4 a00 = {0.f,0.f,0.f,0.f}, a01 = a00, a10 = a00, a11 = a00;
      a00 = __builtin_amdgcn_mfma_f32_16x16x32_bf16(ah0, bH0, a00, 0, 0, 0);
      a00 = __builtin_amdgcn_mfma_f32_16x16x32_bf16(ah0, bL0, a00, 0, 0, 0);
      a00 = __builtin_amdgcn_mfma_f32_16x16x32_bf16(al0, bH0, a00, 0, 0, 0);
      a01 = __builtin_amdgcn_mfma_f32_16x16x32_bf16(ah0, bH1, a01, 0, 0, 0);
      a01 = __builtin_amdgcn_mfma_f32_16x16x32_bf16(ah0, bL1, a01, 0, 0, 0);
      a01 = __builtin_amdgcn_mfma_f32_16x16x32_bf16(al0, bH1, a01, 0, 0, 0);
      a10 = __builtin_amdgcn_mfma_f32_16x16x32_bf16(ah1, bH0, a10, 0, 0, 0);
      a10 = __builtin_amdgcn_mfma_f32_16x16x32_bf16(ah1, bL0, a10, 0, 0, 0);
      a10 = __builtin_amdgcn_mfma_f32_16x16x32_bf16(al1, bH0, a10, 0, 0, 0);
      a11 = __builtin_amdgcn_mfma_f32_16x16x32_bf16(ah1, bH1, a11, 0, 0, 0);
      a11 = __builtin_amdgcn_mfma_f32_16x16x32_bf16(ah1, bL1, a11, 0, 0, 0);
      a11 = __builtin_amdgcn_mfma_f32_16x16x32_bf16(al1, bH1, a11, 0, 0, 0);
      float m0 = fmaxf(fmaxf(a00[0], a00[1]), fmaxf(a00[2], a00[3]));
      float m1 = fmaxf(fmaxf(a01[0], a01[1]), fmaxf(a01[2], a01[3]));
      if (quad == 0) { m0 = fmaxf(m0, a10[0]); m1 = fmaxf(m1, a11[0]); }
      m0 = fmaxf(m0, __shfl_xor(m0, 16)); m0 = fmaxf(m0, __shfl_xor(m0, 32));
      m1 = fmaxf(m1, __shfl_xor(m1, 16)); m1 = fmaxf(m1, __shfl_xor(m1, 32));
      if (quad == 0) {
        xs[ck*4 + wv][l15]      = fmaxf(m0 + bias0, 0.f);    // x2 = relu(max + b2b)
        xs[ck*4 + wv][16 + l15] = fmaxf(m1 + bias1, 0.f);
      }
    }
    __syncthreads();
  }
  if (tid < CH) {                                   // wave 0: block max -> atomic max
    float m2 = xs[0][c];
    #pragma unroll
    for (int r = 1; r < NPB2; ++r) m2 = fmaxf(m2, xs[r][c]);
    int old = atomicMax(&g_gmaxi[g*CH + c], __float_as_int(m2));
    asm volatile("" :: "v"(old));                   // consume -> vmcnt wait -> performed
  }
  if (tid == 0) {                                   // same wave: maxes performed first
    int rank = atomicAdd(&g_cnt[g], 1);
    slast = (rank == BPG2 - 1) ? 1 : 0;
  }
  __syncthreads();
  if (slast) {                                      // last block of this graph: head
    __builtin_amdgcn_fence(__ATOMIC_ACQUIRE, "agent");   // one L2 inv per graph (8 total)
    if (tid < CH) gm2[c] = __int_as_float(((volatile int*)g_gmaxi)[g*CH + c]);
    __syncthreads();
    if (tid < NCLS) {
      float s = g_wts[OBC + tid];
      #pragma unroll
      for (int f = 0; f < CH; ++f) s += gm2[f] * g_wts[OWC + f*NCLS + tid];
      out[g*NCLS + tid] = s;                        // float32 out (reference dtype)
    }
    if (tid < CH) atomicExch(&g_gmaxi[g*CH + tid], 0);   // reset for graph replay
    if (tid == 0) atomicExch(&g_cnt[g], 0);
  }
}

extern "C" void kernel_launch(void* const* d_in, const int* in_sizes, int n_in,
                              void* d_out, int out_size, void* d_ws, size_t ws_size,
                              hipStream_t stream) {
  const void* pos = d_in[0];
  const void* nrm = d_in[1];
  // d_in[2] = batch (int32) -- unused, batches are uniform
  const void* w1a = d_in[3];
  const void* b1a = d_in[4];
  const void* w1b = d_in[5];
  const void* b1b = d_in[6];
  const void* w2a = d_in[7];
  const void* b2a = d_in[8];
  const void* w2b = d_in[9];
  const void* b2b = d_in[10];
  const void* wc  = d_in[11];
  const void* bc  = d_in[12];

  prep_kernel<<<MM/256, 256, 0, stream>>>(pos, nrm, w1a, b1a, w1b, b1b,
                                          w2a, b2a, w2b, b2b, wc, bc);
  knn_conv1_kernel<<<NBLK, 512, 0, stream>>>();
  conv2_kernel<<<NBLK2, 256, 0, stream>>>((float*)d_out);
}

// Round 10
// 195.966 us; speedup vs baseline: 1.1060x; 1.0662x over previous
//
#include <hip/hip_runtime.h>
#include <hip/hip_bf16.h>
#include <math.h>

#define NB 8
#define NN 4096
#define KK 16
#define MM (NB*NN)
#define CH 32
#define SLOTS 17
#define NCLS 40
#define BIG 3.0e38f
#define CAP 96         // survivors ~25-27 incl. self; ballot-push drops extras safely
#define NPB 32         // nodes (=queries) per block
#define NBLK (MM/NPB)  // 1024 blocks for knn_conv1 / conv2
#define BPG (NBLK/NB)  // 128 conv2 blocks per graph
#define HROW 36        // h1s row stride (f32): 144B -> 16B-aligned, 2-way banks (free)
#define HALF 2048      // knn tile half size (points)

// Weight table offsets (floats)
#define OW1A 0
#define OB1A 128
#define OW1B 160
#define OB1B 1184
#define OW2A 1216
#define OB2A 2368
#define OW2B 2400
#define OB2B 3424
#define OWC  3456
#define OBC  4736
#define NWTS 4776

typedef short short8 __attribute__((ext_vector_type(8)));
typedef float f32x4  __attribute__((ext_vector_type(4)));
typedef float f32x2  __attribute__((ext_vector_type(2)));

// Module-global scratch (~21 MB): no assumptions about ws_size.
__device__ float4 g_pos4[MM];
__device__ float4 g_nrm4[MM];
__device__ int    g_nbr[MM*KK];
__device__ float  g_u[MM*CH];
__device__ float  g_wts[NWTS];
__device__ int    g_gmaxi[NB*CH];     // per-graph channel maxima (atomic, int-keyed f32>=0)
__device__ int    g_cnt[NB];          // per-graph done-counter (self-resetting)
__device__ __align__(16) float4 g_fe4[MM*SLOTS];   // PPF features cached conv1 -> conv2
// Pre-split (bf16 hi/lo) + pre-swizzled B-fragments for 16x16x32 MFMA:
// [ntile][hi/lo][lane][j] with value = W[k=(lane>>4)*8+j][n=ntile*16+(lane&15)]
__device__ __align__(16) unsigned short g_wfrag1[2][2][64][8];
__device__ __align__(16) unsigned short g_wfrag2[2][2][64][8];

__device__ __forceinline__ float bf(const __hip_bfloat16 x) { return __bfloat162float(x); }

__device__ __forceinline__ float ldf(const void* p, int i, bool f32) {
  return f32 ? ((const float*)p)[i] : bf(((const __hip_bfloat16*)p)[i]);
}

__device__ __forceinline__ float angf(float ax, float ay, float az,
                                      float bx, float by, float bz) {
  float cx = ay*bz - az*by;
  float cy = az*bx - ax*bz;
  float cz = ax*by - ay*bx;
  float s  = cx*cx + cy*cy + cz*cz;
  float cn = s > 0.f ? sqrtf(s) : 0.f;
  float d  = ax*bx + ay*by + az*bz;
  return (cn > 0.f || d != 0.f) ? atan2f(cn, d) : 0.f;
}

__device__ __forceinline__ void ppf4(const float4 pi, const float4 ni,
                                     const float4 pj, const float4 nj, float* f) {
  float px = pj.x - pi.x, py = pj.y - pi.y, pz = pj.z - pi.z;
  float s = px*px + py*py + pz*pz;
  f[0] = s > 0.f ? sqrtf(s) : 0.f;
  f[1] = angf(ni.x, ni.y, ni.z, px, py, pz);
  f[2] = angf(nj.x, nj.y, nj.z, px, py, pz);
  f[3] = angf(ni.x, ni.y, ni.z, nj.x, nj.y, nj.z);
}

// monotone f32 -> u32 key (order-preserving for all finite floats)
__device__ __forceinline__ unsigned int fkey(float f) {
  unsigned int u = __float_as_uint(f);
  return (u & 0x80000000u) ? ~u : (u | 0x80000000u);
}
__device__ __forceinline__ float funkey(unsigned int k) {
  unsigned int u = (k & 0x80000000u) ? (k ^ 0x80000000u) : ~k;
  return __uint_as_float(u);
}

__device__ __forceinline__ unsigned int mbcnt64(unsigned long long m) {
  return __builtin_amdgcn_mbcnt_hi((unsigned int)(m >> 32),
         __builtin_amdgcn_mbcnt_lo((unsigned int)m, 0u));
}

// split f32 -> bf16 hi/lo bit patterns
__device__ __forceinline__ void bsplit(float v, unsigned short* hi, unsigned short* lo) {
  __hip_bfloat16 h = __float2bfloat16(v);
  float hf = __bfloat162float(h);
  __hip_bfloat16 l = __float2bfloat16(v - hf);
  *hi = *reinterpret_cast<unsigned short*>(&h);
  *lo = *reinterpret_cast<unsigned short*>(&l);
}

// read 8 f32 from LDS row, split into hi/lo bf16 A-fragments (registers)
__device__ __forceinline__ void afrag(const float* row, short8* ah, short8* al) {
  float4 a = *(const float4*)row;
  float4 b = *(const float4*)(row + 4);
  unsigned short h, l;
  #pragma unroll
  for (int j = 0; j < 4; ++j) {
    bsplit((&a.x)[j], &h, &l); (*ah)[j]   = (short)h; (*al)[j]   = (short)l;
    bsplit((&b.x)[j], &h, &l); (*ah)[j+4] = (short)h; (*al)[j+4] = (short)l;
  }
}

// flat g_wts index -> source array element (for distributed weight conversion)
__device__ __forceinline__ float ldwt(int i, bool f32,
    const void* w1a, const void* b1a, const void* w1b, const void* b1b,
    const void* w2a, const void* b2a, const void* w2b, const void* b2b,
    const void* wc, const void* bc) {
  if (i < OB1A) return ldf(w1a, i - OW1A, f32);
  if (i < OW1B) return ldf(b1a, i - OB1A, f32);
  if (i < OB1B) return ldf(w1b, i - OW1B, f32);
  if (i < OW2A) return ldf(b1b, i - OB1B, f32);
  if (i < OB2A) return ldf(w2a, i - OW2A, f32);
  if (i < OW2B) return ldf(b2a, i - OB2A, f32);
  if (i < OB2B) return ldf(w2b, i - OW2B, f32);
  if (i < OWC)  return ldf(b2b, i - OB2B, f32);
  if (i < OBC)  return ldf(wc,  i - OWC,  f32);
  return ldf(bc, i - OBC, f32);
}

// ---------------- prep: dtype vote (per-block, same verdict) + inputs->float4.
// Weight work DISTRIBUTED: frag tables -> blocks 0-15; flat g_wts -> blocks 16-34.
__global__ __launch_bounds__(256) void prep_kernel(
    const void* __restrict__ pos, const void* __restrict__ nrm,
    const void* w1a, const void* b1a, const void* w1b, const void* b1b,
    const void* w2a, const void* b2a, const void* w2b, const void* b2b,
    const void* wc, const void* bc) {
  __shared__ int sflag;
  const int tid = threadIdx.x;
  const int bid = blockIdx.x;
  const int base = bid << 8;
  if (tid < 64) {                                   // wave 0: local dtype vote
    const float* nf = (const float*)nrm;
    const __hip_bfloat16* nh = (const __hip_bfloat16*)nrm;
    int n = base + tid;
    float x = nf[3*n], y = nf[3*n+1], z = nf[3*n+2];
    float ss = x*x + y*y + z*z;
    bool okf = (ss > 0.98f && ss < 1.02f);
    float a = bf(nh[3*n]), b2 = bf(nh[3*n+1]), c2 = bf(nh[3*n+2]);
    float sb = a*a + b2*b2 + c2*c2;
    bool okb = (sb > 0.95f && sb < 1.05f);
    unsigned long long mf = __ballot(okf), mb = __ballot(okb);
    if (tid == 0) sflag = (__popcll(mf) >= __popcll(mb)) ? 1 : 0;
  }
  __syncthreads();
  const bool f32 = sflag != 0;
  {
    int i = base + tid;
    float x = ldf(pos, 3*i, f32), y = ldf(pos, 3*i+1, f32), z = ldf(pos, 3*i+2, f32);
    g_pos4[i] = make_float4(x, y, z, x*x + y*y + z*z);
    float a = ldf(nrm, 3*i, f32), bb = ldf(nrm, 3*i+1, f32), cc = ldf(nrm, 3*i+2, f32);
    g_nrm4[i] = make_float4(a, bb, cc, 0.f);
  }
  if (bid < 16) {                                   // frag tables: 16 blocks x 256 entries
    int t = (bid << 8) + tid;
    int which = t >> 11;                 // 0 = w1b, 1 = w2b
    int r = t & 2047;
    int tt = r >> 10;  r &= 1023;
    int hl = r >> 9;   r &= 511;
    int ln = r >> 3;
    int j  = r & 7;
    int k = (ln >> 4)*8 + j;
    int c = tt*16 + (ln & 15);
    float wv = ldf(which ? w2b : w1b, k*CH + c, f32);
    unsigned short hi, lo;
    bsplit(wv, &hi, &lo);
    unsigned short v = hl ? lo : hi;
    if (which) g_wfrag2[tt][hl][ln][j] = v;
    else       g_wfrag1[tt][hl][ln][j] = v;
  } else if (bid < 35) {                            // g_wts: 19 blocks x 256 floats
    int i = ((bid - 16) << 8) + tid;
    if (i < NWTS)
      g_wts[i] = ldwt(i, f32, w1a, b1a, w1b, b1b, w2a, b2a, w2b, b2b, wc, bc);
  }
}

// ---------------- knn + conv1 fused: 1024 blocks x 512 thr, 32 q/block ------------------
// R7 version (measured 103.0 us; session best). knn: 2-half LDS tile (24KB, 8x
// L2-traffic suppressor -- R5 lesson); packed-pair distances; 16-step bisection on
// 16-bit keys; ballot push (no atomics, self-loop included -> exact-f64 rank 0,
// neighbors ranks 1..16); filter processes half 1 first (resident). Ranking: 64-lane
// f64 bitonic (shuffle-only) with recompute fallback for m>64. Natural VGPR (R3
// lesson: forced occupancy -> 21MB spill traffic). R8's half-sample/bitonic-T and
// R9's conv2 256-thr restructure both regressed and are reverted.
__global__ __launch_bounds__(512) void knn_conv1_kernel() {
  __shared__ __align__(16) union SU {
    struct {
      float sx[HALF], sy[HALF], sz[HALF];           // 24576 B (half tile, SoA)
      unsigned short ilst[NPB][CAP];                //  6144 B
    } k;                                            // 30720 B
    struct {
      float fe[NPB*SLOTS][4];                       //  8704 B (544 edges)
      float h1s[152*HROW];                          // 21888 B (150 max row read + pad)
      float wsaT[32*HROW];                          //  4608 B (w2a[0:32] as [c][k])
      float xs[NPB][CH];                            //  4096 B
    } c;                                            // 39296 B
  } u;
  __shared__ unsigned short nbrs[NPB][KK];          //  1024 B (persists knn -> conv1)

  const int tid  = threadIdx.x;
  const int w    = tid >> 6, lane = tid & 63;
  const int blk  = blockIdx.x;
  const int b    = blk >> 7;                        // 128 blocks per batch
  const int qb   = (blk & 127) << 5;                // node base within batch
  const float4* bp = g_pos4 + b*NN;

  // query coefficients (global read; -2x is exact so x = -0.5*q2x recovers f32 coord)
  float q2x[4], q2y[4], q2z[4];
  #pragma unroll
  for (int qq = 0; qq < 4; ++qq) {
    float4 qv = bp[qb + (w << 2) + qq];
    q2x[qq] = -2.f*qv.x; q2y[qq] = -2.f*qv.y; q2z[qq] = -2.f*qv.z;
  }

  const f32x2* sx2 = (const f32x2*)u.k.sx;
  const f32x2* sy2 = (const f32x2*)u.k.sy;
  const f32x2* sz2 = (const f32x2*)u.k.sz;

  // ---- min pass over halves {0,1}: d' = |o|^2 - 2 q.o (shifted squared distance) ----
  float mn[4];
  #pragma unroll
  for (int qq = 0; qq < 4; ++qq) mn[qq] = BIG;
  #pragma unroll 1
  for (int h = 0; h < 2; ++h) {
    #pragma unroll
    for (int k = 0; k < 4; ++k) {                   // stage half (32KB global -> 24KB LDS)
      int idx = k*512 + tid;
      float4 o = bp[h*HALF + idx];
      u.k.sx[idx] = o.x; u.k.sy[idx] = o.y; u.k.sz[idx] = o.z;
    }
    __syncthreads();
    #pragma unroll 4
    for (int it = 0; it < 16; ++it) {
      int p = it*64 + lane;                         // pair index within half
      f32x2 ox = sx2[p], oy = sy2[p], oz = sz2[p];
      f32x2 ow = __builtin_elementwise_fma(oz, oz,
                 __builtin_elementwise_fma(oy, oy, ox*ox));
      #pragma unroll
      for (int qq = 0; qq < 4; ++qq) {
        f32x2 qx = {q2x[qq], q2x[qq]};
        f32x2 qy = {q2y[qq], q2y[qq]};
        f32x2 qz = {q2z[qq], q2z[qq]};
        f32x2 d = __builtin_elementwise_fma(qx, ox,
                  __builtin_elementwise_fma(qy, oy,
                  __builtin_elementwise_fma(qz, oz, ow)));
        mn[qq] = fminf(fminf(d[0], d[1]), mn[qq]);  // -> v_min3_f32
      }
    }
    if (h == 0) __syncthreads();                    // half reads done before re-stage
  }

  // ---- 16-step bisection over 16-bit truncated keys (threshold bucket rounded UP).
  // Invariant (any candidate->lane mapping): minimal bucket T with >=17 lane-mins <= T
  // => >=17 candidates <= T => d17 <= T => filter superset is safe.
  unsigned int key[4], lo[4], hi[4];
  #pragma unroll
  for (int qq = 0; qq < 4; ++qq) { key[qq] = fkey(mn[qq]) >> 16; lo[qq] = 0u; hi[qq] = 0xFFFFu; }
  #pragma unroll 1
  for (int s = 0; s < 16; ++s) {
    #pragma unroll
    for (int qq = 0; qq < 4; ++qq) {
      unsigned int mid = (lo[qq] + hi[qq]) >> 1;
      int c = (int)__popcll(__ballot(key[qq] <= mid));
      if (c >= 17) hi[qq] = mid; else lo[qq] = mid + 1;
    }
  }
  float Tf[4];
  #pragma unroll
  for (int qq = 0; qq < 4; ++qq) {
    float T = funkey((hi[qq] << 16) | 0xFFFFu);     // >= exact 17th smallest (incl self)
    Tf[qq] = T + 4e-5f + 1e-5f*fabsf(T);            // margin >> f32 d' abs error
  }

  // ---- filter pass, halves {1, 0}: half 1 is still resident -> no re-stage ----
  unsigned int scnt[4];
  #pragma unroll
  for (int qq = 0; qq < 4; ++qq) scnt[qq] = 0u;
  #pragma unroll 1
  for (int hh = 0; hh < 2; ++hh) {
    const int h = 1 - hh;                           // process resident half first
    if (hh == 1) {                                  // re-stage half 0
      __syncthreads();                              // all waves done reading half 1
      #pragma unroll
      for (int k = 0; k < 4; ++k) {
        int idx = k*512 + tid;
        float4 o = bp[h*HALF + idx];
        u.k.sx[idx] = o.x; u.k.sy[idx] = o.y; u.k.sz[idx] = o.z;
      }
      __syncthreads();
    }
    #pragma unroll 2
    for (int it = 0; it < 16; ++it) {
      int p = it*64 + lane;
      int gidx = h*HALF + 2*p;                      // global (in-batch) candidate idx
      f32x2 ox = sx2[p], oy = sy2[p], oz = sz2[p];
      f32x2 ow = __builtin_elementwise_fma(oz, oz,
                 __builtin_elementwise_fma(oy, oy, ox*ox));
      #pragma unroll
      for (int qq = 0; qq < 4; ++qq) {
        f32x2 qx = {q2x[qq], q2x[qq]};
        f32x2 qy = {q2y[qq], q2y[qq]};
        f32x2 qz = {q2z[qq], q2z[qq]};
        f32x2 d = __builtin_elementwise_fma(qx, ox,
                  __builtin_elementwise_fma(qy, oy,
                  __builtin_elementwise_fma(qz, oz, ow)));
        bool h0 = d[0] <= Tf[qq];
        bool h1 = d[1] <= Tf[qq];
        unsigned long long mk0 = __ballot(h0);
        unsigned long long mk1 = __ballot(h1);
        if (mk0 | mk1) {
          unsigned int cbase = scnt[qq];
          if (h0) {
            unsigned int pos = cbase + mbcnt64(mk0);
            if (pos < CAP) u.k.ilst[(w<<2)|qq][pos] = (unsigned short)gidx;
          }
          cbase += (unsigned int)__popcll(mk0);
          if (h1) {
            unsigned int pos = cbase + mbcnt64(mk1);
            if (pos < CAP) u.k.ilst[(w<<2)|qq][pos] = (unsigned short)(gidx + 1);
          }
          scnt[qq] = cbase + (unsigned int)__popcll(mk1);
        }
      }
    }
  }

  // ---- ranking: 64-lane bitonic sort by exact-f64 (d, idx); lane r = rank r ----
  #pragma unroll 1
  for (int qq = 0; qq < 4; ++qq) {
    const int ql = (w << 2) | qq;
    const int m = min((int)scnt[qq], CAP);
    const double mx = (double)(-0.5f*q2x[qq]);
    const double my_ = (double)(-0.5f*q2y[qq]);
    const double mz = (double)(-0.5f*q2z[qq]);
    const double sqme = (mx*mx + my_*my_) + mz*mz;
    if (m <= 64) {
      double d; int idx;
      if (lane < m) {
        int ci = u.k.ilst[ql][lane];
        float4 cv = bp[ci];
        double ox = (double)cv.x, oy = (double)cv.y, oz = (double)cv.z;
        double sqo = (ox*ox + oy*oy) + oz*oz;
        double dt  = (mx*ox + my_*oy) + mz*oz;
        d = (sqme + sqo) - 2.0*dt;
        idx = ci;
      } else { d = 1.0e300; idx = 0x7fffffff; }
      #pragma unroll
      for (int k = 2; k <= 64; k <<= 1) {
        #pragma unroll
        for (int j = k >> 1; j >= 1; j >>= 1) {
          double pd = __shfl_xor(d, j);
          int    pi = __shfl_xor(idx, j);
          bool mineLess = (d < pd) || (d == pd && idx < pi);
          bool wantMin  = (((lane & j) == 0) == ((lane & k) == 0));
          if (mineLess != wantMin) { d = pd; idx = pi; }
        }
      }
      if (lane >= 1 && lane <= KK) {                // rank 0 = self (exact d = 0)
        nbrs[ql][lane-1] = (unsigned short)idx;
        g_nbr[(b*NN + qb + ql)*KK + (lane-1)] = b*NN + idx;
      }
    } else {
      // cold fallback (64 < m <= CAP): recompute-based rank, global reads only
      for (int e = lane; e < m; e += 64) {
        int myi = u.k.ilst[ql][e];
        float4 cv = bp[myi];
        double ox = (double)cv.x, oy = (double)cv.y, oz = (double)cv.z;
        double myd = (sqme + ((ox*ox + oy*oy) + oz*oz))
                   - 2.0*((mx*ox + my_*oy) + mz*oz);
        int rank = 0;
        for (int o = 0; o < m; ++o) {
          int oi = u.k.ilst[ql][o];
          float4 ov = bp[oi];
          double px = (double)ov.x, py = (double)ov.y, pz = (double)ov.z;
          double od = (sqme + ((px*px + py*py) + pz*pz))
                    - 2.0*((mx*px + my_*py) + mz*pz);
          rank += (od < myd) || (od == myd && oi < myi);
        }
        if (rank >= 1 && rank <= KK) {
          nbrs[ql][rank-1] = (unsigned short)myi;
          g_nbr[(b*NN + qb + ql)*KK + (rank-1)] = b*NN + myi;
        }
      }
    }
  }

  // ---- conv1 phase (same block; no grid sync) ----
  const int c32 = tid & 31;
  const int quad = lane >> 4, l15 = lane & 15;
  float w1a_c[4];
  #pragma unroll
  for (int f = 0; f < 4; ++f) w1a_c[f] = g_wts[OW1A + f*CH + c32];
  const float b1a_c = g_wts[OB1A + c32];
  short8 bH0 = *(const short8*)&g_wfrag1[0][0][lane][0];
  short8 bL0 = *(const short8*)&g_wfrag1[0][1][lane][0];
  short8 bH1 = *(const short8*)&g_wfrag1[1][0][lane][0];
  short8 bL1 = *(const short8*)&g_wfrag1[1][1][lane][0];
  const float bias0 = g_wts[OB1B + l15];
  const float bias1 = g_wts[OB1B + 16 + l15];

  __syncthreads();                                  // union.k dead past this point

  for (int i2 = tid; i2 < 1024; i2 += 512) {        // stage w2a[0:32] transposed
    int k = i2 >> 5, cc = i2 & 31;
    u.c.wsaT[cc*HROW + k] = g_wts[OW2A + i2];
  }
  const int nbb = b*NN + qb;                        // global node base of this block
  for (int e = tid; e < NPB*SLOTS; e += 512) {      // 544 edges, balanced ppf staging
    int ns = e / 17, slot = e - ns*17;
    int ig = nbb + ns;
    int jg = (slot < KK) ? (b*NN + (int)nbrs[ns][slot]) : ig;  // slot 16 = self
    float f[4];
    ppf4(g_pos4[ig], g_nrm4[ig], g_pos4[jg], g_nrm4[jg], f);
    float4 fv = make_float4(f[0], f[1], f[2], f[3]);
    *(float4*)u.c.fe[e] = fv;
    g_fe4[(size_t)nbb*SLOTS + e] = fv;              // cache for conv2 (bit-identical)
  }
  __syncthreads();

  #pragma unroll 1
  for (int ck = 0; ck < 4; ++ck) {                  // 4 chunks x 8 nodes, 1 node/wave
    #pragma unroll
    for (int it = 0; it < 9; ++it) {                // h-phase: 136 rows x 32 ch
      int idx = it*512 + tid;
      int e = idx >> 5;                             // c == tid&31
      if (e < 136) {
        float4 f4 = *(const float4*)u.c.fe[ck*136 + e];
        float h = b1a_c + f4.x*w1a_c[0] + f4.y*w1a_c[1] + f4.z*w1a_c[2] + f4.w*w1a_c[3];
        u.c.h1s[e*HROW + c32] = fmaxf(h, 0.f);
      }
    }
    __syncthreads();
    {                                               // MFMA: wave w owns node ck*8+w
      const int rbase = w*17;
      short8 ah0, al0, ah1, al1;
      afrag(&u.c.h1s[(rbase      + l15)*HROW + quad*8], &ah0, &al0);
      afrag(&u.c.h1s[(rbase + 16 + l15)*HROW + quad*8], &ah1, &al1);
      f32x4 a00 = {0.f,0.f,0.f,0.f}, a01 = a00, a10 = a00, a11 = a00;
      a00 = __builtin_amdgcn_mfma_f32_16x16x32_bf16(ah0, bH0, a00, 0, 0, 0);
      a00 = __builtin_amdgcn_mfma_f32_16x16x32_bf16(ah0, bL0, a00, 0, 0, 0);
      a00 = __builtin_amdgcn_mfma_f32_16x16x32_bf16(al0, bH0, a00, 0, 0, 0);
      a01 = __builtin_amdgcn_mfma_f32_16x16x32_bf16(ah0, bH1, a01, 0, 0, 0);
      a01 = __builtin_amdgcn_mfma_f32_16x16x32_bf16(ah0, bL1, a01, 0, 0, 0);
      a01 = __builtin_amdgcn_mfma_f32_16x16x32_bf16(al0, bH1, a01, 0, 0, 0);
      a10 = __builtin_amdgcn_mfma_f32_16x16x32_bf16(ah1, bH0, a10, 0, 0, 0);
      a10 = __builtin_amdgcn_mfma_f32_16x16x32_bf16(ah1, bL0, a10, 0, 0, 0);
      a10 = __builtin_amdgcn_mfma_f32_16x16x32_bf16(al1, bH0, a10, 0, 0, 0);
      a11 = __builtin_amdgcn_mfma_f32_16x16x32_bf16(ah1, bH1, a11, 0, 0, 0);
      a11 = __builtin_amdgcn_mfma_f32_16x16x32_bf16(ah1, bL1, a11, 0, 0, 0);
      a11 = __builtin_amdgcn_mfma_f32_16x16x32_bf16(al1, bH1, a11, 0, 0, 0);
      float m0 = fmaxf(fmaxf(a00[0], a00[1]), fmaxf(a00[2], a00[3]));
      float m1 = fmaxf(fmaxf(a01[0], a01[1]), fmaxf(a01[2], a01[3]));
      if (quad == 0) { m0 = fmaxf(m0, a10[0]); m1 = fmaxf(m1, a11[0]); }
      m0 = fmaxf(m0, __shfl_xor(m0, 16)); m0 = fmaxf(m0, __shfl_xor(m0, 32));
      m1 = fmaxf(m1, __shfl_xor(m1, 16)); m1 = fmaxf(m1, __shfl_xor(m1, 32));
      if (quad == 0) {
        u.c.xs[ck*8 + w][l15]      = fmaxf(m0 + bias0, 0.f);  // x1 = relu(max + b1b)
        u.c.xs[ck*8 + w][16 + l15] = fmaxf(m1 + bias1, 0.f);
      }
    }
    __syncthreads();
  }
  #pragma unroll
  for (int it = 0; it < 2; ++it) {                  // u-epilogue: 32 nodes x 32 ch
    int ns = it*16 + (tid >> 5);
    float uu = 0.f;
    #pragma unroll
    for (int k4 = 0; k4 < 8; ++k4) {
      float4 x4 = *(const float4*)&u.c.xs[ns][4*k4];
      float4 w4 = *(const float4*)&u.c.wsaT[c32*HROW + 4*k4];
      uu += x4.x*w4.x + x4.y*w4.y + x4.z*w4.z + x4.w*w4.w;
    }
    g_u[(nbb + ns)*CH + c32] = uu;                  // u = x1 @ w2a[0:32,:]
  }
}

// ---------------- conv2 + fused head via device-scope ATOMICS (no fences on hot path) --
// R7 version (session best): 512 thr / 32 nodes, g_u gather software-prefetched one
// chunk ahead into registers (issued after the h-phase barrier, in flight across the
// MFMA phase). R9's 256-thr/16-node restructure regressed ~10us (replicated per-block
// overhead ate the narrower-barrier gain) and is reverted.
__global__ __launch_bounds__(512) void conv2_kernel(float* __restrict__ out) {
  __shared__ __align__(16) float fe[NPB*SLOTS][4];  //  8704 B
  __shared__ int jn[NPB*SLOTS];                     //  2176 B
  __shared__ __align__(16) float h1s[152*HROW];     // 21888 B
  __shared__ float xs[NPB][CH];                     //  4096 B
  __shared__ float gm2[CH];
  __shared__ int slast;
  const int tid = threadIdx.x;
  const int c = tid & 31;
  const int s16 = tid >> 5;                         // row-group 0..15
  const int lane = tid & 63, wv = tid >> 6;
  const int quad = lane >> 4, l15 = lane & 15;
  const int node0 = blockIdx.x << 5;                // 32 nodes/block
  const int g = blockIdx.x >> 7;                    // graph index (128 blocks/graph)
  float w2aL_c[4];
  #pragma unroll
  for (int f = 0; f < 4; ++f) w2aL_c[f] = g_wts[OW2A + (CH + f)*CH + c];
  const float b2a_c = g_wts[OB2A + c];
  short8 bH0 = *(const short8*)&g_wfrag2[0][0][lane][0];
  short8 bL0 = *(const short8*)&g_wfrag2[0][1][lane][0];
  short8 bH1 = *(const short8*)&g_wfrag2[1][0][lane][0];
  short8 bL1 = *(const short8*)&g_wfrag2[1][1][lane][0];
  const float bias0 = g_wts[OB2B + l15];
  const float bias1 = g_wts[OB2B + 16 + l15];

  for (int e = tid; e < NPB*SLOTS; e += 512) {      // stage jn + cached fe (coalesced)
    int ns = e / 17, slot = e - ns*17;
    int i = node0 + ns;
    jn[e] = (slot < KK) ? g_nbr[i*KK + slot] : i;
    *(float4*)fe[e] = g_fe4[(size_t)node0*SLOTS + e];
  }
  __syncthreads();

  float upf[9];                                     // u prefetch (chunk ahead)
  #pragma unroll
  for (int it = 0; it < 9; ++it) {                  // prefetch chunk 0
    int e = it*16 + s16;
    int ee = (e < 136) ? e : 135;                   // clamp (tail rows unused)
    upf[it] = g_u[jn[ee]*CH + c];
  }

  #pragma unroll 1
  for (int ck = 0; ck < 4; ++ck) {
    #pragma unroll
    for (int it = 0; it < 9; ++it) {                // h-phase: 136 rows x 32 ch
      int e = it*16 + s16;                          // == (it*512+tid)>>5
      if (e < 136) {
        float4 f4 = *(const float4*)fe[ck*136 + e];
        float h = b2a_c + upf[it] + f4.x*w2aL_c[0] + f4.y*w2aL_c[1]
                + f4.z*w2aL_c[2] + f4.w*w2aL_c[3];
        h1s[e*HROW + c] = fmaxf(h, 0.f);
      }
    }
    __syncthreads();
    if (ck < 3) {                                   // prefetch next chunk's u rows;
      #pragma unroll                                // in flight across the MFMA phase
      for (int it = 0; it < 9; ++it) {
        int e = it*16 + s16;
        int ee = (e < 136) ? e : 135;
        upf[it] = g_u[jn[(ck+1)*136 + ee]*CH + c];
      }
    }
    {                                               // MFMA: wave wv owns node ck*8+wv
      const int rbase = wv*17;
      short8 ah0, al0, ah1, al1;
      afrag(&h1s[(rbase      + l15)*HROW + quad*8], &ah0, &al0);
      afrag(&h1s[(rbase + 16 + l15)*HROW + quad*8], &ah1, &al1);
      f32x4 a00 = {0.f,0.f,0.f,0.f}, a01 = a00, a10 = a00, a11 = a00;
      a00 = __builtin_amdgcn_mfma_f32_16x16x32_bf16(ah0, bH0, a00, 0, 0, 0);
      a00 = __builtin_amdgcn_mfma_f32_16x16x32_bf16(ah0, bL0, a00, 0, 0, 0);
      a00 = __builtin_amdgcn_mfma_f32_16x16x32_bf16(al0, bH0, a00, 0, 0, 0);
      a01 = __builtin_amdgcn_mfma_f32_16x16x32_bf16(ah0, bH1, a01, 0, 0, 0);
      a01 = __builtin_amdgcn_mfma_f32_16x16x32_bf16(ah0, bL1, a01, 0, 0, 0);
      a01 = __builtin_amdgcn_mfma_f32_16x16x32_bf16(al0, bH1, a01, 0, 0, 0);
      a10 = __builtin_amdgcn_mfma_f32_16x16x32_bf16(ah1, bH0, a10, 0, 0, 0);
      a10 = __builtin_amdgcn_mfma_f32_16x16x32_bf16(ah1, bL0, a10, 0, 0, 0);
      a10 = __builtin_amdgcn_mfma_f32_16x16x32_bf16(al1, bH0, a10, 0, 0, 0);
      a11 = __builtin_amdgcn_mfma_f32_16x16x32_bf16(ah1, bH1, a11, 0, 0, 0);
      a11 = __builtin_amdgcn_mfma_f32_16x16x32_bf16(ah1, bL1, a11, 0, 0, 0);
      a11 = __builtin_amdgcn_mfma_f32_16x16x32_bf16(al1, bH1, a11, 0, 0, 0);
      float m0 = fmaxf(fmaxf(a00[0], a00[1]), fmaxf(a00[2], a00[3]));
      float m1 = fmaxf(fmaxf(a01[0], a01[1]), fmaxf(a01[2], a01[3]));
      if (quad == 0) { m0 = fmaxf(m0, a10[0]); m1 = fmaxf(m1, a11[0]); }
      m0 = fmaxf(m0, __shfl_xor(m0, 16)); m0 = fmaxf(m0, __shfl_xor(m0, 32));
      m1 = fmaxf(m1, __shfl_xor(m1, 16)); m1 = fmaxf(m1, __shfl_xor(m1, 32));
      if (quad == 0) {
        xs[ck*8 + wv][l15]      = fmaxf(m0 + bias0, 0.f);    // x2 = relu(max + b2b)
        xs[ck*8 + wv][16 + l15] = fmaxf(m1 + bias1, 0.f);
      }
    }
    __syncthreads();
  }
  if (tid < CH) {                                   // wave 0: block max -> atomic max
    float m2 = xs[0][c];
    #pragma unroll
    for (int r = 1; r < NPB; ++r) m2 = fmaxf(m2, xs[r][c]);
    int old = atomicMax(&g_gmaxi[g*CH + c], __float_as_int(m2));
    asm volatile("" :: "v"(old));                   // consume -> vmcnt wait -> performed
  }
  if (tid == 0) {                                   // same wave: maxes performed first
    int rank = atomicAdd(&g_cnt[g], 1);
    slast = (rank == BPG - 1) ? 1 : 0;
  }
  __syncthreads();
  if (slast) {                                      // last block of this graph: head
    __builtin_amdgcn_fence(__ATOMIC_ACQUIRE, "agent");   // one L2 inv per graph (8 total)
    if (tid < CH) gm2[c] = __int_as_float(((volatile int*)g_gmaxi)[g*CH + c]);
    __syncthreads();
    if (tid < NCLS) {
      float s = g_wts[OBC + tid];
      #pragma unroll
      for (int f = 0; f < CH; ++f) s += gm2[f] * g_wts[OWC + f*NCLS + tid];
      out[g*NCLS + tid] = s;                        // float32 out (reference dtype)
    }
    if (tid < CH) atomicExch(&g_gmaxi[g*CH + tid], 0);   // reset for graph replay
    if (tid == 0) atomicExch(&g_cnt[g], 0);
  }
}

extern "C" void kernel_launch(void* const* d_in, const int* in_sizes, int n_in,
                              void* d_out, int out_size, void* d_ws, size_t ws_size,
                              hipStream_t stream) {
  const void* pos = d_in[0];
  const void* nrm = d_in[1];
  // d_in[2] = batch (int32) -- unused, batches are uniform
  const void* w1a = d_in[3];
  const void* b1a = d_in[4];
  const void* w1b = d_in[5];
  const void* b1b = d_in[6];
  const void* w2a = d_in[7];
  const void* b2a = d_in[8];
  const void* w2b = d_in[9];
  const void* b2b = d_in[10];
  const void* wc  = d_in[11];
  const void* bc  = d_in[12];

  prep_kernel<<<MM/256, 256, 0, stream>>>(pos, nrm, w1a, b1a, w1b, b1b,
                                          w2a, b2a, w2b, b2b, wc, bc);
  knn_conv1_kernel<<<NBLK, 512, 0, stream>>>();
  conv2_kernel<<<NBLK, 512, 0, stream>>>((float*)d_out);
}